// Round 10
// baseline (251.421 us; speedup 1.0000x reference)
//
#include <hip/hip_runtime.h>
#include <hip/hip_fp16.h>
#include <math.h>

#define FDIM 128

static inline size_t align512(size_t x) { return (x + 511) & ~((size_t)511); }

// ---- zero kernel (hipMemsetAsync's rocclr fill showed 44us in-graph) ----
__global__ void zero_kernel(int* __restrict__ p, int n) {
    int i = blockIdx.x * 256 + threadIdx.x;
    if (i < n) p[i] = 0;
}

// ---- degree histogram, 4 edges/thread, non-returning atomics ------------
__global__ __launch_bounds__(256) void count4_kernel(const int* __restrict__ dst,
                                                     int* __restrict__ cnt, int ne) {
    int base = (blockIdx.x * 256 + threadIdx.x) * 4;
    if (base + 3 < ne) {
        int4 d = *(const int4*)(dst + base);
        atomicAdd(&cnt[d.x], 1);
        atomicAdd(&cnt[d.y], 1);
        atomicAdd(&cnt[d.z], 1);
        atomicAdd(&cnt[d.w], 1);
    } else {
        for (int i = base; i < ne; i++) atomicAdd(&cnt[dst[i]], 1);
    }
}

// ---- fused GEMM (out_fp16 = X@W) + optional CSR scatter -----------------
// GEMM: 64x64 output tile, 256 threads, thread = 2 rows x 8 cols (acc 16 VGPR).
// Grid gemm part = 2*ceil(N/64) = 1564 -> ~6 blocks/CU (R9: 782 = 3/CU was
// grid-limited at VGPR-allowed 4/CU). LDS = X[64][36] + W[32][64] = 17.2 KB.
// Scatter fused as extra blocks: its waves idle on atomic/store latency
// (VALU 0.4%) and overlap the FMA-bound gemm waves on the same CUs.
// NOTE: no min-waves clause (R4: VGPR cap => acc spill, 131MB scratch writes).
__global__ __launch_bounds__(256) void gemm_scatter(const float* __restrict__ X,
                                                    const float* __restrict__ W,
                                                    __half* __restrict__ out, int nrows,
                                                    int gemm_blocks,
                                                    const int* __restrict__ src,
                                                    const int* __restrict__ dstE,
                                                    const float* __restrict__ dinv,
                                                    int* __restrict__ cursor,
                                                    int2* __restrict__ csr_pack, int ne) {
    __shared__ __align__(16) float Xl[64 * 36];   // one 32-k slice of X, pad->36
    __shared__ __align__(16) float Wl[32 * 64];   // one 32-k x 64-col slice of W
    if ((int)blockIdx.x >= gemm_blocks) {
        // ---- scatter part: 4 edges/thread ----
        int base = (((int)blockIdx.x - gemm_blocks) * 256 + threadIdx.x) * 4;
        if (base + 3 < ne) {
            int4 s4 = *(const int4*)(src + base);
            int4 d4 = *(const int4*)(dstE + base);
            int p0 = atomicAdd(&cursor[d4.x], 1);
            int p1 = atomicAdd(&cursor[d4.y], 1);
            int p2 = atomicAdd(&cursor[d4.z], 1);
            int p3 = atomicAdd(&cursor[d4.w], 1);
            float v0 = dinv[s4.x], v1 = dinv[s4.y], v2 = dinv[s4.z], v3 = dinv[s4.w];
            int2 q0; q0.x = s4.x; q0.y = __float_as_int(v0);
            int2 q1; q1.x = s4.y; q1.y = __float_as_int(v1);
            int2 q2; q2.x = s4.z; q2.y = __float_as_int(v2);
            int2 q3; q3.x = s4.w; q3.y = __float_as_int(v3);
            csr_pack[p0] = q0;
            csr_pack[p1] = q1;
            csr_pack[p2] = q2;
            csr_pack[p3] = q3;
        } else {
            for (int i = base; i < ne; i++) {
                int d = dstE[i], s = src[i];
                int pos = atomicAdd(&cursor[d], 1);
                int2 p;
                p.x = s;
                p.y = __float_as_int(dinv[s]);
                csr_pack[pos] = p;
            }
        }
        return;
    }
    // ---- gemm part ----
    int rb = blockIdx.x >> 1;         // row block
    int ch = blockIdx.x & 1;          // column half (64 cols)
    int tid = threadIdx.x;
    int row0 = rb * 64;
    int nrow_t = min(64, nrows - row0);

    int rg = tid >> 3;                // 0..31 -> rows rg, rg+32
    int c0 = (tid & 7) * 4;           // col base within half; cols c0 + 32*j
    float4 acc[2][2];
    #pragma unroll
    for (int a = 0; a < 2; a++)
        #pragma unroll
        for (int j = 0; j < 2; j++) acc[a][j] = make_float4(0.f, 0.f, 0.f, 0.f);

    for (int kc = 0; kc < 4; kc++) {
        __syncthreads();
        // stage X chunk: nrow_t rows x 32 cols (8 float4/row)
        for (int idx = tid; idx < nrow_t * 8; idx += 256) {
            int r = idx >> 3, c4 = idx & 7;
            *(float4*)(&Xl[r * 36 + c4 * 4]) =
                *(const float4*)(X + (size_t)(row0 + r) * FDIM + kc * 32 + c4 * 4);
        }
        // stage W chunk: rows kc*32..+31, cols ch*64..+63 (512 float4)
        for (int idx = tid; idx < 512; idx += 256) {
            int r = idx >> 4, c4 = idx & 15;
            *(float4*)(&Wl[r * 64 + c4 * 4]) =
                *(const float4*)(W + (size_t)(kc * 32 + r) * FDIM + ch * 64 + c4 * 4);
        }
        __syncthreads();
        #pragma unroll
        for (int k4 = 0; k4 < 8; k4++) {       // 4 k at a time
            float4 xr[2];
            xr[0] = *(const float4*)(&Xl[rg * 36 + k4 * 4]);
            xr[1] = *(const float4*)(&Xl[(rg + 32) * 36 + k4 * 4]);
            #pragma unroll
            for (int kk = 0; kk < 4; kk++) {
                float xs0 = (kk == 0) ? xr[0].x : (kk == 1) ? xr[0].y
                          : (kk == 2) ? xr[0].z : xr[0].w;
                float xs1 = (kk == 0) ? xr[1].x : (kk == 1) ? xr[1].y
                          : (kk == 2) ? xr[1].z : xr[1].w;
                int k = k4 * 4 + kk;
                #pragma unroll
                for (int j = 0; j < 2; j++) {
                    float4 w = *(const float4*)(&Wl[k * 64 + c0 + 32 * j]);
                    acc[0][j].x = fmaf(xs0, w.x, acc[0][j].x);
                    acc[0][j].y = fmaf(xs0, w.y, acc[0][j].y);
                    acc[0][j].z = fmaf(xs0, w.z, acc[0][j].z);
                    acc[0][j].w = fmaf(xs0, w.w, acc[0][j].w);
                    acc[1][j].x = fmaf(xs1, w.x, acc[1][j].x);
                    acc[1][j].y = fmaf(xs1, w.y, acc[1][j].y);
                    acc[1][j].z = fmaf(xs1, w.z, acc[1][j].z);
                    acc[1][j].w = fmaf(xs1, w.w, acc[1][j].w);
                }
            }
        }
    }
    #pragma unroll
    for (int a = 0; a < 2; a++) {
        int row = row0 + rg + 32 * a;
        if (row < nrows) {
            #pragma unroll
            for (int j = 0; j < 2; j++) {
                __half2 h0 = __floats2half2_rn(acc[a][j].x, acc[a][j].y);
                __half2 h1 = __floats2half2_rn(acc[a][j].z, acc[a][j].w);
                __half2* p = (__half2*)(out + (size_t)row * FDIM + ch * 64 + c0 + 32 * j);
                p[0] = h0; p[1] = h1;
            }
        }
    }
}

// ---- Hierarchical exclusive scan ----------------------------------------
__global__ __launch_bounds__(256) void scan_block_sums(const int* __restrict__ cnt,
                                                       int* __restrict__ bsum, int n) {
    __shared__ int red[256];
    int tid = threadIdx.x;
    int idx = blockIdx.x * 256 + tid;
    red[tid] = (idx < n) ? cnt[idx] : 0;
    __syncthreads();
    for (int off = 128; off > 0; off >>= 1) {
        if (tid < off) red[tid] += red[tid + off];
        __syncthreads();
    }
    if (tid == 0) bsum[blockIdx.x] = red[0];
}

__global__ __launch_bounds__(1024) void scan_bsums(int* __restrict__ bsum, int nb) {
    __shared__ int sh[1024];
    int tid = threadIdx.x;
    int v = (tid < nb) ? bsum[tid] : 0;
    sh[tid] = v;
    __syncthreads();
    for (int off = 1; off < 1024; off <<= 1) {
        int t = (tid >= off) ? sh[tid - off] : 0;
        __syncthreads();
        sh[tid] += t;
        __syncthreads();
    }
    if (tid < nb) bsum[tid] = sh[tid] - v;   // exclusive
}

// also emits dinv = 1/sqrt(deg+1)
__global__ __launch_bounds__(256) void scan_final(const int* __restrict__ cnt,
                                                  const int* __restrict__ bsum,
                                                  int* __restrict__ rowptr,
                                                  int* __restrict__ cursor,
                                                  float* __restrict__ dinv, int n) {
    __shared__ int sh[256];
    int tid = threadIdx.x;
    int idx = blockIdx.x * 256 + tid;
    int c = (idx < n) ? cnt[idx] : 0;
    sh[tid] = c;
    __syncthreads();
    for (int off = 1; off < 256; off <<= 1) {
        int t = (tid >= off) ? sh[tid - off] : 0;
        __syncthreads();
        sh[tid] += t;
        __syncthreads();
    }
    if (idx < n) {
        int excl = sh[tid] - c + bsum[blockIdx.x];
        rowptr[idx] = excl;
        cursor[idx] = excl;
        dinv[idx] = 1.0f / sqrtf((float)(c + 1));
        if (idx == n - 1) rowptr[n] = excl + c;
    }
}

// ---- Aggregate + norm + bias + ELU --------------------------------------
// G is fp16 (row = 256 B); 8 nodes/block, 32 threads/node, 8 B/lane,
// edge loop unrolled x8. acc/output fp32.
__global__ __launch_bounds__(256) void agg_elu(const __half* __restrict__ G,
                                               const int* __restrict__ rowptr,
                                               const int2* __restrict__ csr_pack,
                                               const float* __restrict__ dinv,
                                               const float* __restrict__ bias,
                                               float* __restrict__ out, int n) {
    int node = blockIdx.x * 8 + (threadIdx.x >> 5);
    int c = threadIdx.x & 31;
    if (node >= n) return;
    const float2* G2 = (const float2*)G;   // 8 B units; row stride = 32
    int beg = rowptr[node], end = rowptr[node + 1];
    float dn = dinv[node];

    float2 sraw = G2[(size_t)node * 32 + c];
    __half2 sh0 = *(__half2*)&sraw.x, sh1 = *(__half2*)&sraw.y;
    float2 s0f = __half22float2(sh0), s1f = __half22float2(sh1);
    float4 acc;
    acc.x = dn * s0f.x; acc.y = dn * s0f.y; acc.z = dn * s1f.x; acc.w = dn * s1f.y;

    int e = beg;
    for (; e + 7 < end; e += 8) {
        int2 p0 = csr_pack[e],     p1 = csr_pack[e + 1];
        int2 p2 = csr_pack[e + 2], p3 = csr_pack[e + 3];
        int2 p4 = csr_pack[e + 4], p5 = csr_pack[e + 5];
        int2 p6 = csr_pack[e + 6], p7 = csr_pack[e + 7];
        float2 r0 = G2[(size_t)p0.x * 32 + c];
        float2 r1 = G2[(size_t)p1.x * 32 + c];
        float2 r2 = G2[(size_t)p2.x * 32 + c];
        float2 r3 = G2[(size_t)p3.x * 32 + c];
        float2 r4 = G2[(size_t)p4.x * 32 + c];
        float2 r5 = G2[(size_t)p5.x * 32 + c];
        float2 r6 = G2[(size_t)p6.x * 32 + c];
        float2 r7 = G2[(size_t)p7.x * 32 + c];
        #define ACC_EDGE(P, R)                                              \
        {                                                                   \
            float d = __int_as_float(P.y);                                  \
            __half2 h0 = *(__half2*)&R.x, h1 = *(__half2*)&R.y;             \
            float2 f0 = __half22float2(h0), f1 = __half22float2(h1);        \
            acc.x = fmaf(d, f0.x, acc.x); acc.y = fmaf(d, f0.y, acc.y);     \
            acc.z = fmaf(d, f1.x, acc.z); acc.w = fmaf(d, f1.y, acc.w);     \
        }
        ACC_EDGE(p0, r0) ACC_EDGE(p1, r1) ACC_EDGE(p2, r2) ACC_EDGE(p3, r3)
        ACC_EDGE(p4, r4) ACC_EDGE(p5, r5) ACC_EDGE(p6, r6) ACC_EDGE(p7, r7)
    }
    for (; e < end; e++) {
        int2 p = csr_pack[e];
        float2 r = G2[(size_t)p.x * 32 + c];
        ACC_EDGE(p, r)
    }
    #undef ACC_EDGE

    float4 b = ((const float4*)bias)[c];
    float4 o;
    o.x = fmaf(dn, acc.x, b.x); o.y = fmaf(dn, acc.y, b.y);
    o.z = fmaf(dn, acc.z, b.z); o.w = fmaf(dn, acc.w, b.w);
    o.x = (o.x > 0.f) ? o.x : expm1f(o.x);
    o.y = (o.y > 0.f) ? o.y : expm1f(o.y);
    o.z = (o.z > 0.f) ? o.z : expm1f(o.z);
    o.w = (o.w > 0.f) ? o.w : expm1f(o.w);
    ((float4*)out)[(size_t)node * 32 + c] = o;
}

// ---- Global mean pool (contiguous nper-node graphs) ---------------------
__global__ __launch_bounds__(256) void pool_kernel(const float* __restrict__ H,
                                                   float* __restrict__ out,
                                                   int nper, int ngraphs) {
    __shared__ float tmp[128];
    int g = blockIdx.x;
    int f = threadIdx.x & 127;
    int half = threadIdx.x >> 7;
    if (g >= ngraphs) return;
    const float* base = H + (size_t)g * nper * FDIM;
    float acc = 0.f;
    for (int i = half; i < nper; i += 2) acc += base[(size_t)i * FDIM + f];
    if (half == 1) tmp[f] = acc;
    __syncthreads();
    if (half == 0) out[(size_t)g * FDIM + f] = (acc + tmp[f]) * (1.0f / (float)nper);
}

extern "C" void kernel_launch(void* const* d_in, const int* in_sizes, int n_in,
                              void* d_out, int out_size, void* d_ws, size_t ws_size,
                              hipStream_t stream) {
    const float* x  = (const float*)d_in[0];
    const float* W1 = (const float*)d_in[1];
    const float* b1 = (const float*)d_in[2];
    const float* W2 = (const float*)d_in[3];
    const float* b2 = (const float*)d_in[4];
    const int* edge_index = (const int*)d_in[5];
    float* out = (float*)d_out;

    int N = in_sizes[0] / FDIM;
    int E = in_sizes[5] / 2;
    int G = out_size / FDIM;
    int nper = N / G;
    const int* src = edge_index;
    const int* dst = edge_index + E;

    char* ws = (char*)d_ws;
    size_t off = 0;
    int* cnt = (int*)(ws + off);        off = align512(off + (size_t)N * 4);
    int* rowptr = (int*)(ws + off);     off = align512(off + (size_t)(N + 1) * 4);
    int* cursor = (int*)(ws + off);     off = align512(off + (size_t)N * 4);
    float* dinv = (float*)(ws + off);   off = align512(off + (size_t)N * 4);
    int* bsum = (int*)(ws + off);       off = align512(off + (size_t)1024 * 4);
    int2* csr_pack = (int2*)(ws + off); off = align512(off + (size_t)E * 8);
    __half* bufG = (__half*)(ws + off); off = align512(off + (size_t)N * FDIM * 2);
    float* bufB = (float*)(ws + off);   off = align512(off + (size_t)N * FDIM * 4);
    (void)ws_size;

    int nb = (N + 255) / 256;                        // scan blocks (<=1024)
    int gemm_grid = 2 * ((N + 63) / 64);             // 1564
    int agg_grid = (N + 7) / 8;
    int e4_grid = (E / 4 + 255) / 256;               // 782 (count & scatter)

    zero_kernel<<<nb, 256, 0, stream>>>(cnt, N);
    count4_kernel<<<e4_grid, 256, 0, stream>>>(dst, cnt, E);
    scan_block_sums<<<nb, 256, 0, stream>>>(cnt, bsum, N);
    scan_bsums<<<1, 1024, 0, stream>>>(bsum, nb);
    scan_final<<<nb, 256, 0, stream>>>(cnt, bsum, rowptr, cursor, dinv, N);

    // layer-1 GEMM overlapped with CSR scatter (independent until agg1)
    gemm_scatter<<<gemm_grid + e4_grid, 256, 0, stream>>>(
        x, W1, bufG, N, gemm_grid, src, dst, dinv, cursor, csr_pack, E);

    agg_elu<<<agg_grid, 256, 0, stream>>>(bufG, rowptr, csr_pack, dinv, b1, bufB, N);
    // layer-2 GEMM (no scatter part)
    gemm_scatter<<<gemm_grid, 256, 0, stream>>>(
        bufB, W2, bufG, N, gemm_grid, src, dst, dinv, cursor, csr_pack, 0);
    agg_elu<<<agg_grid, 256, 0, stream>>>(bufG, rowptr, csr_pack, dinv, b2, bufB, N);
    pool_kernel<<<G, 256, 0, stream>>>(bufB, out, nper, G);
}

// Round 11
// 249.952 us; speedup vs baseline: 1.0059x; 1.0059x over previous
//
#include <hip/hip_runtime.h>
#include <hip/hip_fp16.h>
#include <math.h>

#define FDIM 128

static inline size_t align512(size_t x) { return (x + 511) & ~((size_t)511); }

// ---- zero kernel (hipMemsetAsync's rocclr fill showed 44us in-graph) ----
__global__ void zero_kernel(int* __restrict__ p, int n) {
    int i = blockIdx.x * 256 + threadIdx.x;
    if (i < n) p[i] = 0;
}

// ---- degree histogram, 4 edges/thread, non-returning atomics ------------
__global__ __launch_bounds__(256) void count4_kernel(const int* __restrict__ dst,
                                                     int* __restrict__ cnt, int ne) {
    int base = (blockIdx.x * 256 + threadIdx.x) * 4;
    if (base + 3 < ne) {
        int4 d = *(const int4*)(dst + base);
        atomicAdd(&cnt[d.x], 1);
        atomicAdd(&cnt[d.y], 1);
        atomicAdd(&cnt[d.z], 1);
        atomicAdd(&cnt[d.w], 1);
    } else {
        for (int i = base; i < ne; i++) atomicAdd(&cnt[dst[i]], 1);
    }
}

// ---- fused GEMM (out_fp16 = X@W) + optional CSR scatter -----------------
// GEMM: R9's proven tile — 64 rows/block, 256 threads, thread = 2 rows x 16
// cols (full 128-col rows per block: output lines stay block-private; R10's
// 64-col split caused 5x partial-line write amplification, 79us).
// Grid 782 -> ~5 blocks/CU at VGPR 92. LDS = X[64][36] + W[32][128] = 25.6 KB.
// Scatter fused as extra blocks: its waves idle on atomic/store latency
// (VALU 0.4%) and overlap the FMA-bound gemm waves (R10's valid idea).
// NOTE: no min-waves clause (R4: VGPR cap => acc spill, 131MB scratch writes).
#define TROWS 64
__global__ __launch_bounds__(256) void gemm_scatter(const float* __restrict__ X,
                                                    const float* __restrict__ W,
                                                    __half* __restrict__ out, int nrows,
                                                    int gemm_blocks,
                                                    const int* __restrict__ src,
                                                    const int* __restrict__ dstE,
                                                    const float* __restrict__ dinv,
                                                    int* __restrict__ cursor,
                                                    int2* __restrict__ csr_pack, int ne) {
    __shared__ __align__(16) float Xl[TROWS * 36];   // one 32-k slice of X, pad->36
    __shared__ __align__(16) float Wl[32 * 128];     // one 32-k slice of W
    if ((int)blockIdx.x >= gemm_blocks) {
        // ---- scatter part: 4 edges/thread ----
        int base = (((int)blockIdx.x - gemm_blocks) * 256 + threadIdx.x) * 4;
        if (base + 3 < ne) {
            int4 s4 = *(const int4*)(src + base);
            int4 d4 = *(const int4*)(dstE + base);
            int p0 = atomicAdd(&cursor[d4.x], 1);
            int p1 = atomicAdd(&cursor[d4.y], 1);
            int p2 = atomicAdd(&cursor[d4.z], 1);
            int p3 = atomicAdd(&cursor[d4.w], 1);
            float v0 = dinv[s4.x], v1 = dinv[s4.y], v2 = dinv[s4.z], v3 = dinv[s4.w];
            int2 q0; q0.x = s4.x; q0.y = __float_as_int(v0);
            int2 q1; q1.x = s4.y; q1.y = __float_as_int(v1);
            int2 q2; q2.x = s4.z; q2.y = __float_as_int(v2);
            int2 q3; q3.x = s4.w; q3.y = __float_as_int(v3);
            csr_pack[p0] = q0;
            csr_pack[p1] = q1;
            csr_pack[p2] = q2;
            csr_pack[p3] = q3;
        } else {
            for (int i = base; i < ne; i++) {
                int d = dstE[i], s = src[i];
                int pos = atomicAdd(&cursor[d], 1);
                int2 p;
                p.x = s;
                p.y = __float_as_int(dinv[s]);
                csr_pack[pos] = p;
            }
        }
        return;
    }
    // ---- gemm part ----
    int tid = threadIdx.x;
    int row0 = blockIdx.x * TROWS;
    int nrow_t = min(TROWS, nrows - row0);

    int rg = tid >> 3;           // 0..31 -> rows rg, rg+32
    int c0 = (tid & 7) * 4;      // col base; cols c0 + 32*j
    float4 acc[2][4];
    #pragma unroll
    for (int a = 0; a < 2; a++)
        #pragma unroll
        for (int j = 0; j < 4; j++) acc[a][j] = make_float4(0.f, 0.f, 0.f, 0.f);

    for (int kc = 0; kc < 4; kc++) {
        __syncthreads();
        for (int idx = tid; idx < nrow_t * 8; idx += 256) {
            int r = idx >> 3, c4 = idx & 7;
            *(float4*)(&Xl[r * 36 + c4 * 4]) =
                *(const float4*)(X + (size_t)(row0 + r) * FDIM + kc * 32 + c4 * 4);
        }
        for (int idx = tid; idx < 1024; idx += 256)
            *(float4*)(&Wl[idx * 4]) = *(const float4*)(W + (size_t)kc * 32 * FDIM + idx * 4);
        __syncthreads();
        #pragma unroll
        for (int k4 = 0; k4 < 8; k4++) {        // 4 k at a time
            float4 xr[2];
            #pragma unroll
            for (int a = 0; a < 2; a++)
                xr[a] = *(const float4*)(&Xl[(rg + 32 * a) * 36 + k4 * 4]);
            #pragma unroll
            for (int kk = 0; kk < 4; kk++) {
                float xs[2];
                #pragma unroll
                for (int a = 0; a < 2; a++)
                    xs[a] = (kk == 0) ? xr[a].x : (kk == 1) ? xr[a].y
                          : (kk == 2) ? xr[a].z : xr[a].w;
                int k = k4 * 4 + kk;
                #pragma unroll
                for (int j = 0; j < 4; j++) {
                    float4 w = *(const float4*)(&Wl[k * FDIM + c0 + 32 * j]);
                    #pragma unroll
                    for (int a = 0; a < 2; a++) {
                        acc[a][j].x = fmaf(xs[a], w.x, acc[a][j].x);
                        acc[a][j].y = fmaf(xs[a], w.y, acc[a][j].y);
                        acc[a][j].z = fmaf(xs[a], w.z, acc[a][j].z);
                        acc[a][j].w = fmaf(xs[a], w.w, acc[a][j].w);
                    }
                }
            }
        }
    }
    #pragma unroll
    for (int a = 0; a < 2; a++) {
        int row = row0 + rg + 32 * a;
        if (row < nrows) {
            #pragma unroll
            for (int j = 0; j < 4; j++) {
                __half2 h0 = __floats2half2_rn(acc[a][j].x, acc[a][j].y);
                __half2 h1 = __floats2half2_rn(acc[a][j].z, acc[a][j].w);
                __half2* p = (__half2*)(out + (size_t)row * FDIM + c0 + 32 * j);
                p[0] = h0; p[1] = h1;
            }
        }
    }
}

// ---- Hierarchical exclusive scan ----------------------------------------
__global__ __launch_bounds__(256) void scan_block_sums(const int* __restrict__ cnt,
                                                       int* __restrict__ bsum, int n) {
    __shared__ int red[256];
    int tid = threadIdx.x;
    int idx = blockIdx.x * 256 + tid;
    red[tid] = (idx < n) ? cnt[idx] : 0;
    __syncthreads();
    for (int off = 128; off > 0; off >>= 1) {
        if (tid < off) red[tid] += red[tid + off];
        __syncthreads();
    }
    if (tid == 0) bsum[blockIdx.x] = red[0];
}

__global__ __launch_bounds__(1024) void scan_bsums(int* __restrict__ bsum, int nb) {
    __shared__ int sh[1024];
    int tid = threadIdx.x;
    int v = (tid < nb) ? bsum[tid] : 0;
    sh[tid] = v;
    __syncthreads();
    for (int off = 1; off < 1024; off <<= 1) {
        int t = (tid >= off) ? sh[tid - off] : 0;
        __syncthreads();
        sh[tid] += t;
        __syncthreads();
    }
    if (tid < nb) bsum[tid] = sh[tid] - v;   // exclusive
}

// also emits dinv = 1/sqrt(deg+1)
__global__ __launch_bounds__(256) void scan_final(const int* __restrict__ cnt,
                                                  const int* __restrict__ bsum,
                                                  int* __restrict__ rowptr,
                                                  int* __restrict__ cursor,
                                                  float* __restrict__ dinv, int n) {
    __shared__ int sh[256];
    int tid = threadIdx.x;
    int idx = blockIdx.x * 256 + tid;
    int c = (idx < n) ? cnt[idx] : 0;
    sh[tid] = c;
    __syncthreads();
    for (int off = 1; off < 256; off <<= 1) {
        int t = (tid >= off) ? sh[tid - off] : 0;
        __syncthreads();
        sh[tid] += t;
        __syncthreads();
    }
    if (idx < n) {
        int excl = sh[tid] - c + bsum[blockIdx.x];
        rowptr[idx] = excl;
        cursor[idx] = excl;
        dinv[idx] = 1.0f / sqrtf((float)(c + 1));
        if (idx == n - 1) rowptr[n] = excl + c;
    }
}

// ---- Aggregate + norm + bias + ELU --------------------------------------
// G is fp16 (row = 256 B); 16 nodes/block, 16 threads/node, 16 B float4/lane
// (half the load instrs of the 32-lane x 8B variant), edge loop unrolled x8.
__global__ __launch_bounds__(256) void agg_elu(const __half* __restrict__ G,
                                               const int* __restrict__ rowptr,
                                               const int2* __restrict__ csr_pack,
                                               const float* __restrict__ dinv,
                                               const float* __restrict__ bias,
                                               float* __restrict__ out, int n) {
    int node = blockIdx.x * 16 + (threadIdx.x >> 4);
    int c = threadIdx.x & 15;              // float4 (16 B) column
    if (node >= n) return;
    const float4* G4 = (const float4*)G;   // row stride = 16 float4s
    int beg = rowptr[node], end = rowptr[node + 1];
    float dn = dinv[node];

    float acc[8];
    {
        float4 sraw = G4[(size_t)node * 16 + c];
        __half2 h; float2 f;
        h = *(__half2*)&sraw.x; f = __half22float2(h); acc[0] = dn * f.x; acc[1] = dn * f.y;
        h = *(__half2*)&sraw.y; f = __half22float2(h); acc[2] = dn * f.x; acc[3] = dn * f.y;
        h = *(__half2*)&sraw.z; f = __half22float2(h); acc[4] = dn * f.x; acc[5] = dn * f.y;
        h = *(__half2*)&sraw.w; f = __half22float2(h); acc[6] = dn * f.x; acc[7] = dn * f.y;
    }

    #define ACC_EDGE(P, R)                                                   \
    {                                                                        \
        float d = __int_as_float(P.y);                                       \
        __half2 h; float2 f;                                                 \
        h = *(__half2*)&R.x; f = __half22float2(h);                          \
        acc[0] = fmaf(d, f.x, acc[0]); acc[1] = fmaf(d, f.y, acc[1]);        \
        h = *(__half2*)&R.y; f = __half22float2(h);                          \
        acc[2] = fmaf(d, f.x, acc[2]); acc[3] = fmaf(d, f.y, acc[3]);        \
        h = *(__half2*)&R.z; f = __half22float2(h);                          \
        acc[4] = fmaf(d, f.x, acc[4]); acc[5] = fmaf(d, f.y, acc[5]);        \
        h = *(__half2*)&R.w; f = __half22float2(h);                          \
        acc[6] = fmaf(d, f.x, acc[6]); acc[7] = fmaf(d, f.y, acc[7]);        \
    }

    int e = beg;
    for (; e + 7 < end; e += 8) {
        int2 p0 = csr_pack[e],     p1 = csr_pack[e + 1];
        int2 p2 = csr_pack[e + 2], p3 = csr_pack[e + 3];
        int2 p4 = csr_pack[e + 4], p5 = csr_pack[e + 5];
        int2 p6 = csr_pack[e + 6], p7 = csr_pack[e + 7];
        float4 r0 = G4[(size_t)p0.x * 16 + c];
        float4 r1 = G4[(size_t)p1.x * 16 + c];
        float4 r2 = G4[(size_t)p2.x * 16 + c];
        float4 r3 = G4[(size_t)p3.x * 16 + c];
        float4 r4 = G4[(size_t)p4.x * 16 + c];
        float4 r5 = G4[(size_t)p5.x * 16 + c];
        float4 r6 = G4[(size_t)p6.x * 16 + c];
        float4 r7 = G4[(size_t)p7.x * 16 + c];
        ACC_EDGE(p0, r0) ACC_EDGE(p1, r1) ACC_EDGE(p2, r2) ACC_EDGE(p3, r3)
        ACC_EDGE(p4, r4) ACC_EDGE(p5, r5) ACC_EDGE(p6, r6) ACC_EDGE(p7, r7)
    }
    for (; e < end; e++) {
        int2 p = csr_pack[e];
        float4 r = G4[(size_t)p.x * 16 + c];
        ACC_EDGE(p, r)
    }
    #undef ACC_EDGE

    const float4* b4 = (const float4*)bias;
    float4 blo = b4[2 * c], bhi = b4[2 * c + 1];
    float4 vlo, vhi;
    vlo.x = fmaf(dn, acc[0], blo.x); vlo.y = fmaf(dn, acc[1], blo.y);
    vlo.z = fmaf(dn, acc[2], blo.z); vlo.w = fmaf(dn, acc[3], blo.w);
    vhi.x = fmaf(dn, acc[4], bhi.x); vhi.y = fmaf(dn, acc[5], bhi.y);
    vhi.z = fmaf(dn, acc[6], bhi.z); vhi.w = fmaf(dn, acc[7], bhi.w);
    vlo.x = (vlo.x > 0.f) ? vlo.x : expm1f(vlo.x);
    vlo.y = (vlo.y > 0.f) ? vlo.y : expm1f(vlo.y);
    vlo.z = (vlo.z > 0.f) ? vlo.z : expm1f(vlo.z);
    vlo.w = (vlo.w > 0.f) ? vlo.w : expm1f(vlo.w);
    vhi.x = (vhi.x > 0.f) ? vhi.x : expm1f(vhi.x);
    vhi.y = (vhi.y > 0.f) ? vhi.y : expm1f(vhi.y);
    vhi.z = (vhi.z > 0.f) ? vhi.z : expm1f(vhi.z);
    vhi.w = (vhi.w > 0.f) ? vhi.w : expm1f(vhi.w);
    float4* o4 = (float4*)out;
    o4[(size_t)node * 32 + 2 * c] = vlo;
    o4[(size_t)node * 32 + 2 * c + 1] = vhi;
}

// ---- Global mean pool (contiguous nper-node graphs) ---------------------
__global__ __launch_bounds__(256) void pool_kernel(const float* __restrict__ H,
                                                   float* __restrict__ out,
                                                   int nper, int ngraphs) {
    __shared__ float tmp[128];
    int g = blockIdx.x;
    int f = threadIdx.x & 127;
    int half = threadIdx.x >> 7;
    if (g >= ngraphs) return;
    const float* base = H + (size_t)g * nper * FDIM;
    float acc = 0.f;
    for (int i = half; i < nper; i += 2) acc += base[(size_t)i * FDIM + f];
    if (half == 1) tmp[f] = acc;
    __syncthreads();
    if (half == 0) out[(size_t)g * FDIM + f] = (acc + tmp[f]) * (1.0f / (float)nper);
}

extern "C" void kernel_launch(void* const* d_in, const int* in_sizes, int n_in,
                              void* d_out, int out_size, void* d_ws, size_t ws_size,
                              hipStream_t stream) {
    const float* x  = (const float*)d_in[0];
    const float* W1 = (const float*)d_in[1];
    const float* b1 = (const float*)d_in[2];
    const float* W2 = (const float*)d_in[3];
    const float* b2 = (const float*)d_in[4];
    const int* edge_index = (const int*)d_in[5];
    float* out = (float*)d_out;

    int N = in_sizes[0] / FDIM;
    int E = in_sizes[5] / 2;
    int G = out_size / FDIM;
    int nper = N / G;
    const int* src = edge_index;
    const int* dst = edge_index + E;

    char* ws = (char*)d_ws;
    size_t off = 0;
    int* cnt = (int*)(ws + off);        off = align512(off + (size_t)N * 4);
    int* rowptr = (int*)(ws + off);     off = align512(off + (size_t)(N + 1) * 4);
    int* cursor = (int*)(ws + off);     off = align512(off + (size_t)N * 4);
    float* dinv = (float*)(ws + off);   off = align512(off + (size_t)N * 4);
    int* bsum = (int*)(ws + off);       off = align512(off + (size_t)1024 * 4);
    int2* csr_pack = (int2*)(ws + off); off = align512(off + (size_t)E * 8);
    __half* bufG = (__half*)(ws + off); off = align512(off + (size_t)N * FDIM * 2);
    float* bufB = (float*)(ws + off);   off = align512(off + (size_t)N * FDIM * 4);
    (void)ws_size;

    int nb = (N + 255) / 256;                    // scan blocks (<=1024)
    int gemm_grid = (N + TROWS - 1) / TROWS;     // 782
    int agg_grid = (N + 15) / 16;
    int e4_grid = (E / 4 + 255) / 256;           // 782 (count & scatter)

    zero_kernel<<<nb, 256, 0, stream>>>(cnt, N);
    count4_kernel<<<e4_grid, 256, 0, stream>>>(dst, cnt, E);
    scan_block_sums<<<nb, 256, 0, stream>>>(cnt, bsum, N);
    scan_bsums<<<1, 1024, 0, stream>>>(bsum, nb);
    scan_final<<<nb, 256, 0, stream>>>(cnt, bsum, rowptr, cursor, dinv, N);

    // layer-1 GEMM overlapped with CSR scatter (independent until agg1)
    gemm_scatter<<<gemm_grid + e4_grid, 256, 0, stream>>>(
        x, W1, bufG, N, gemm_grid, src, dst, dinv, cursor, csr_pack, E);

    agg_elu<<<agg_grid, 256, 0, stream>>>(bufG, rowptr, csr_pack, dinv, b1, bufB, N);
    // layer-2 GEMM (no scatter part)
    gemm_scatter<<<gemm_grid, 256, 0, stream>>>(
        bufB, W2, bufG, N, gemm_grid, src, dst, dinv, cursor, csr_pack, 0);
    agg_elu<<<agg_grid, 256, 0, stream>>>(bufG, rowptr, csr_pack, dinv, b2, bufB, N);
    pool_kernel<<<G, 256, 0, stream>>>(bufB, out, nper, G);
}

// Round 12
// 247.420 us; speedup vs baseline: 1.0162x; 1.0102x over previous
//
#include <hip/hip_runtime.h>
#include <hip/hip_fp16.h>
#include <math.h>

#define FDIM 128

typedef _Float16 f16x8 __attribute__((ext_vector_type(8)));
typedef float f32x4 __attribute__((ext_vector_type(4)));

static inline size_t align512(size_t x) { return (x + 511) & ~((size_t)511); }

// ---- prep: zero cnt + convert W1,W2 -> fp16 transposed [col][k] ---------
__global__ __launch_bounds__(256) void prep_kernel(int* __restrict__ cnt, int n,
                                                   const float* __restrict__ W1,
                                                   const float* __restrict__ W2,
                                                   __half* __restrict__ W1t,
                                                   __half* __restrict__ W2t, int zb) {
    int b = blockIdx.x;
    if (b < zb) {
        int i = b * 256 + threadIdx.x;
        if (i < n) cnt[i] = 0;
        return;
    }
    int q = b - zb;                              // 0..127 (64 blocks per matrix)
    const float* W = (q < 64) ? W1 : W2;
    __half* Wt = (q < 64) ? W1t : W2t;
    int gid = (q & 63) * 256 + threadIdx.x;      // 0..16383
    int c = gid >> 7, k = gid & 127;
    Wt[(size_t)c * FDIM + k] = __float2half(W[(size_t)k * FDIM + c]);
}

// ---- MFMA GEMM (out_fp16 = fp16(X) @ Wt^T) + optional degree histogram --
// 64 rows/block, 256 threads = 4 waves; wave w owns rows w*16..+15.
// A-frag: lane l = Xl[w*16 + (l&15)][kk*32+(l>>4)*8 .. +8)   (LDS, pad 136)
// B-frag: lane l = Wt[c*16 + (l&15)][kk*32+(l>>4)*8 .. +8)   (global, L2-hot)
// D:      lane l, reg r -> row (l>>4)*4+r, col l&15           (m89-verified)
// R11 lesson: vector-FMA GEMM is LDS-throughput-bound (18 b128/k4 vs 256
// FMA-cyc, 4 waves oversubscribe LDS 3.4x). MFMA cuts LDS bytes/FLOP ~8x.
__global__ __launch_bounds__(256) void gemm_mfma(const float* __restrict__ X,
                                                 const __half* __restrict__ Wt,
                                                 __half* __restrict__ out, int nrows,
                                                 int gemm_blocks,
                                                 const int* __restrict__ dst,
                                                 int* __restrict__ cnt, int ne) {
    __shared__ __half Xl[64 * 136];   // 64 rows x 128 fp16, pad->136 (17.4 KB)
    if ((int)blockIdx.x >= gemm_blocks) {
        // ---- degree histogram: 4 edges/thread ----
        int base = (((int)blockIdx.x - gemm_blocks) * 256 + threadIdx.x) * 4;
        if (base + 3 < ne) {
            int4 d = *(const int4*)(dst + base);
            atomicAdd(&cnt[d.x], 1);
            atomicAdd(&cnt[d.y], 1);
            atomicAdd(&cnt[d.z], 1);
            atomicAdd(&cnt[d.w], 1);
        } else {
            for (int i = base; i < ne; i++) atomicAdd(&cnt[dst[i]], 1);
        }
        return;
    }
    int tid = threadIdx.x;
    int row0 = blockIdx.x * 64;

    // stage X tile fp32 -> fp16 LDS (rows clamped; garbage rows only affect
    // masked output rows — each D row depends only on its own A row)
    for (int i = tid; i < 64 * 32; i += 256) {
        int r = i >> 5, c4 = i & 31;
        int rg = row0 + r;
        if (rg > nrows - 1) rg = nrows - 1;
        float4 v = *(const float4*)(X + (size_t)rg * FDIM + c4 * 4);
        union { __half2 h[2]; int2 i2; } u;
        u.h[0] = __floats2half2_rn(v.x, v.y);
        u.h[1] = __floats2half2_rn(v.z, v.w);
        *(int2*)(&Xl[r * 136 + c4 * 4]) = u.i2;
    }
    __syncthreads();

    int lane = tid & 63;
    int w = tid >> 6;                 // wave id 0..3
    int l15 = lane & 15;
    int kq = lane >> 4;               // k quarter 0..3

    f16x8 a[4];
    #pragma unroll
    for (int kk = 0; kk < 4; kk++)
        a[kk] = *(const f16x8*)(&Xl[(w * 16 + l15) * 136 + kk * 32 + kq * 8]);

    #pragma unroll
    for (int c = 0; c < 8; c++) {
        f32x4 acc = {0.f, 0.f, 0.f, 0.f};
        #pragma unroll
        for (int kk = 0; kk < 4; kk++) {
            f16x8 b = *(const f16x8*)(Wt + (size_t)(c * 16 + l15) * FDIM + kk * 32 + kq * 8);
            acc = __builtin_amdgcn_mfma_f32_16x16x32_f16(a[kk], b, acc, 0, 0, 0);
        }
        int colg = c * 16 + l15;
        #pragma unroll
        for (int r = 0; r < 4; r++) {
            int rowg = row0 + w * 16 + kq * 4 + r;
            if (rowg < nrows)
                out[(size_t)rowg * FDIM + colg] = __float2half(acc[r]);
        }
    }
}

// ---- Hierarchical exclusive scan ----------------------------------------
__global__ __launch_bounds__(256) void scan_block_sums(const int* __restrict__ cnt,
                                                       int* __restrict__ bsum, int n) {
    __shared__ int red[256];
    int tid = threadIdx.x;
    int idx = blockIdx.x * 256 + tid;
    red[tid] = (idx < n) ? cnt[idx] : 0;
    __syncthreads();
    for (int off = 128; off > 0; off >>= 1) {
        if (tid < off) red[tid] += red[tid + off];
        __syncthreads();
    }
    if (tid == 0) bsum[blockIdx.x] = red[0];
}

__global__ __launch_bounds__(1024) void scan_bsums(int* __restrict__ bsum, int nb) {
    __shared__ int sh[1024];
    int tid = threadIdx.x;
    int v = (tid < nb) ? bsum[tid] : 0;
    sh[tid] = v;
    __syncthreads();
    for (int off = 1; off < 1024; off <<= 1) {
        int t = (tid >= off) ? sh[tid - off] : 0;
        __syncthreads();
        sh[tid] += t;
        __syncthreads();
    }
    if (tid < nb) bsum[tid] = sh[tid] - v;   // exclusive
}

// also emits dinv = 1/sqrt(deg+1)
__global__ __launch_bounds__(256) void scan_final(const int* __restrict__ cnt,
                                                  const int* __restrict__ bsum,
                                                  int* __restrict__ rowptr,
                                                  int* __restrict__ cursor,
                                                  float* __restrict__ dinv, int n) {
    __shared__ int sh[256];
    int tid = threadIdx.x;
    int idx = blockIdx.x * 256 + tid;
    int c = (idx < n) ? cnt[idx] : 0;
    sh[tid] = c;
    __syncthreads();
    for (int off = 1; off < 256; off <<= 1) {
        int t = (tid >= off) ? sh[tid - off] : 0;
        __syncthreads();
        sh[tid] += t;
        __syncthreads();
    }
    if (idx < n) {
        int excl = sh[tid] - c + bsum[blockIdx.x];
        rowptr[idx] = excl;
        cursor[idx] = excl;
        dinv[idx] = 1.0f / sqrtf((float)(c + 1));
        if (idx == n - 1) rowptr[n] = excl + c;
    }
}

// ---- CSR scatter: packed (src, dinv[src]), 4 edges/thread ----------------
__global__ __launch_bounds__(256) void scatter_kernel(const int* __restrict__ src,
                                                      const int* __restrict__ dst,
                                                      const float* __restrict__ dinv,
                                                      int* __restrict__ cursor,
                                                      int2* __restrict__ csr_pack,
                                                      int ne) {
    int base = (blockIdx.x * 256 + threadIdx.x) * 4;
    if (base + 3 < ne) {
        int4 s4 = *(const int4*)(src + base);
        int4 d4 = *(const int4*)(dst + base);
        int p0 = atomicAdd(&cursor[d4.x], 1);
        int p1 = atomicAdd(&cursor[d4.y], 1);
        int p2 = atomicAdd(&cursor[d4.z], 1);
        int p3 = atomicAdd(&cursor[d4.w], 1);
        float v0 = dinv[s4.x], v1 = dinv[s4.y], v2 = dinv[s4.z], v3 = dinv[s4.w];
        int2 q0; q0.x = s4.x; q0.y = __float_as_int(v0);
        int2 q1; q1.x = s4.y; q1.y = __float_as_int(v1);
        int2 q2; q2.x = s4.z; q2.y = __float_as_int(v2);
        int2 q3; q3.x = s4.w; q3.y = __float_as_int(v3);
        csr_pack[p0] = q0;
        csr_pack[p1] = q1;
        csr_pack[p2] = q2;
        csr_pack[p3] = q3;
    } else {
        for (int i = base; i < ne; i++) {
            int d = dst[i], s = src[i];
            int pos = atomicAdd(&cursor[d], 1);
            int2 p;
            p.x = s;
            p.y = __float_as_int(dinv[s]);
            csr_pack[pos] = p;
        }
    }
}

// ---- Aggregate + norm + bias + ELU --------------------------------------
// G is fp16 (row = 256 B); 16 nodes/block, 16 threads/node, 16 B float4/lane,
// edge loop unrolled x8. acc/output fp32.
__global__ __launch_bounds__(256) void agg_elu(const __half* __restrict__ G,
                                               const int* __restrict__ rowptr,
                                               const int2* __restrict__ csr_pack,
                                               const float* __restrict__ dinv,
                                               const float* __restrict__ bias,
                                               float* __restrict__ out, int n) {
    int node = blockIdx.x * 16 + (threadIdx.x >> 4);
    int c = threadIdx.x & 15;              // float4 (16 B) column
    if (node >= n) return;
    const float4* G4 = (const float4*)G;   // row stride = 16 float4s
    int beg = rowptr[node], end = rowptr[node + 1];
    float dn = dinv[node];

    float acc[8];
    {
        float4 sraw = G4[(size_t)node * 16 + c];
        __half2 h; float2 f;
        h = *(__half2*)&sraw.x; f = __half22float2(h); acc[0] = dn * f.x; acc[1] = dn * f.y;
        h = *(__half2*)&sraw.y; f = __half22float2(h); acc[2] = dn * f.x; acc[3] = dn * f.y;
        h = *(__half2*)&sraw.z; f = __half22float2(h); acc[4] = dn * f.x; acc[5] = dn * f.y;
        h = *(__half2*)&sraw.w; f = __half22float2(h); acc[6] = dn * f.x; acc[7] = dn * f.y;
    }

    #define ACC_EDGE(P, R)                                                   \
    {                                                                        \
        float d = __int_as_float(P.y);                                       \
        __half2 h; float2 f;                                                 \
        h = *(__half2*)&R.x; f = __half22float2(h);                          \
        acc[0] = fmaf(d, f.x, acc[0]); acc[1] = fmaf(d, f.y, acc[1]);        \
        h = *(__half2*)&R.y; f = __half22float2(h);                          \
        acc[2] = fmaf(d, f.x, acc[2]); acc[3] = fmaf(d, f.y, acc[3]);        \
        h = *(__half2*)&R.z; f = __half22float2(h);                          \
        acc[4] = fmaf(d, f.x, acc[4]); acc[5] = fmaf(d, f.y, acc[5]);        \
        h = *(__half2*)&R.w; f = __half22float2(h);                          \
        acc[6] = fmaf(d, f.x, acc[6]); acc[7] = fmaf(d, f.y, acc[7]);        \
    }

    int e = beg;
    for (; e + 7 < end; e += 8) {
        int2 p0 = csr_pack[e],     p1 = csr_pack[e + 1];
        int2 p2 = csr_pack[e + 2], p3 = csr_pack[e + 3];
        int2 p4 = csr_pack[e + 4], p5 = csr_pack[e + 5];
        int2 p6 = csr_pack[e + 6], p7 = csr_pack[e + 7];
        float4 r0 = G4[(size_t)p0.x * 16 + c];
        float4 r1 = G4[(size_t)p1.x * 16 + c];
        float4 r2 = G4[(size_t)p2.x * 16 + c];
        float4 r3 = G4[(size_t)p3.x * 16 + c];
        float4 r4 = G4[(size_t)p4.x * 16 + c];
        float4 r5 = G4[(size_t)p5.x * 16 + c];
        float4 r6 = G4[(size_t)p6.x * 16 + c];
        float4 r7 = G4[(size_t)p7.x * 16 + c];
        ACC_EDGE(p0, r0) ACC_EDGE(p1, r1) ACC_EDGE(p2, r2) ACC_EDGE(p3, r3)
        ACC_EDGE(p4, r4) ACC_EDGE(p5, r5) ACC_EDGE(p6, r6) ACC_EDGE(p7, r7)
    }
    for (; e < end; e++) {
        int2 p = csr_pack[e];
        float4 r = G4[(size_t)p.x * 16 + c];
        ACC_EDGE(p, r)
    }
    #undef ACC_EDGE

    const float4* b4 = (const float4*)bias;
    float4 blo = b4[2 * c], bhi = b4[2 * c + 1];
    float4 vlo, vhi;
    vlo.x = fmaf(dn, acc[0], blo.x); vlo.y = fmaf(dn, acc[1], blo.y);
    vlo.z = fmaf(dn, acc[2], blo.z); vlo.w = fmaf(dn, acc[3], blo.w);
    vhi.x = fmaf(dn, acc[4], bhi.x); vhi.y = fmaf(dn, acc[5], bhi.y);
    vhi.z = fmaf(dn, acc[6], bhi.z); vhi.w = fmaf(dn, acc[7], bhi.w);
    vlo.x = (vlo.x > 0.f) ? vlo.x : expm1f(vlo.x);
    vlo.y = (vlo.y > 0.f) ? vlo.y : expm1f(vlo.y);
    vlo.z = (vlo.z > 0.f) ? vlo.z : expm1f(vlo.z);
    vlo.w = (vlo.w > 0.f) ? vlo.w : expm1f(vlo.w);
    vhi.x = (vhi.x > 0.f) ? vhi.x : expm1f(vhi.x);
    vhi.y = (vhi.y > 0.f) ? vhi.y : expm1f(vhi.y);
    vhi.z = (vhi.z > 0.f) ? vhi.z : expm1f(vhi.z);
    vhi.w = (vhi.w > 0.f) ? vhi.w : expm1f(vhi.w);
    float4* o4 = (float4*)out;
    o4[(size_t)node * 32 + 2 * c] = vlo;
    o4[(size_t)node * 32 + 2 * c + 1] = vhi;
}

// ---- Global mean pool (contiguous nper-node graphs) ---------------------
__global__ __launch_bounds__(256) void pool_kernel(const float* __restrict__ H,
                                                   float* __restrict__ out,
                                                   int nper, int ngraphs) {
    __shared__ float tmp[128];
    int g = blockIdx.x;
    int f = threadIdx.x & 127;
    int half = threadIdx.x >> 7;
    if (g >= ngraphs) return;
    const float* base = H + (size_t)g * nper * FDIM;
    float acc = 0.f;
    for (int i = half; i < nper; i += 2) acc += base[(size_t)i * FDIM + f];
    if (half == 1) tmp[f] = acc;
    __syncthreads();
    if (half == 0) out[(size_t)g * FDIM + f] = (acc + tmp[f]) * (1.0f / (float)nper);
}

extern "C" void kernel_launch(void* const* d_in, const int* in_sizes, int n_in,
                              void* d_out, int out_size, void* d_ws, size_t ws_size,
                              hipStream_t stream) {
    const float* x  = (const float*)d_in[0];
    const float* W1 = (const float*)d_in[1];
    const float* b1 = (const float*)d_in[2];
    const float* W2 = (const float*)d_in[3];
    const float* b2 = (const float*)d_in[4];
    const int* edge_index = (const int*)d_in[5];
    float* out = (float*)d_out;

    int N = in_sizes[0] / FDIM;
    int E = in_sizes[5] / 2;
    int G = out_size / FDIM;
    int nper = N / G;
    const int* src = edge_index;
    const int* dst = edge_index + E;

    char* ws = (char*)d_ws;
    size_t off = 0;
    int* cnt = (int*)(ws + off);        off = align512(off + (size_t)N * 4);
    int* rowptr = (int*)(ws + off);     off = align512(off + (size_t)(N + 1) * 4);
    int* cursor = (int*)(ws + off);     off = align512(off + (size_t)N * 4);
    float* dinv = (float*)(ws + off);   off = align512(off + (size_t)N * 4);
    int* bsum = (int*)(ws + off);       off = align512(off + (size_t)1024 * 4);
    __half* W1t = (__half*)(ws + off);  off = align512(off + (size_t)FDIM * FDIM * 2);
    __half* W2t = (__half*)(ws + off);  off = align512(off + (size_t)FDIM * FDIM * 2);
    int2* csr_pack = (int2*)(ws + off); off = align512(off + (size_t)E * 8);
    __half* bufG = (__half*)(ws + off); off = align512(off + (size_t)N * FDIM * 2);
    float* bufB = (float*)(ws + off);   off = align512(off + (size_t)N * FDIM * 4);
    (void)ws_size;

    int nb = (N + 255) / 256;                    // scan blocks (<=1024)
    int gemm_grid = (N + 63) / 64;               // 782
    int agg_grid = (N + 15) / 16;
    int e4_grid = (E / 4 + 255) / 256;           // 782 (count & scatter)

    // prep: zero cnt + build fp16 W^T for both layers
    prep_kernel<<<nb + 128, 256, 0, stream>>>(cnt, N, W1, W2, W1t, W2t, nb);
    // layer-1 MFMA GEMM overlapped with degree histogram
    gemm_mfma<<<gemm_grid + e4_grid, 256, 0, stream>>>(
        x, W1t, bufG, N, gemm_grid, dst, cnt, E);
    scan_block_sums<<<nb, 256, 0, stream>>>(cnt, bsum, N);
    scan_bsums<<<1, 1024, 0, stream>>>(bsum, nb);
    scan_final<<<nb, 256, 0, stream>>>(cnt, bsum, rowptr, cursor, dinv, N);
    scatter_kernel<<<e4_grid, 256, 0, stream>>>(src, dst, dinv, cursor, csr_pack, E);

    agg_elu<<<agg_grid, 256, 0, stream>>>(bufG, rowptr, csr_pack, dinv, b1, bufB, N);
    // layer-2 MFMA GEMM (no count part)
    gemm_mfma<<<gemm_grid, 256, 0, stream>>>(
        bufB, W2t, bufG, N, gemm_grid, dst, cnt, 0);
    agg_elu<<<agg_grid, 256, 0, stream>>>(bufG, rowptr, csr_pack, dinv, b2, bufB, N);
    pool_kernel<<<G, 256, 0, stream>>>(bufB, out, nper, G);
}

// Round 13
// 238.491 us; speedup vs baseline: 1.0542x; 1.0374x over previous
//
#include <hip/hip_runtime.h>
#include <hip/hip_fp16.h>
#include <math.h>

#define FDIM 128

typedef _Float16 f16x8 __attribute__((ext_vector_type(8)));
typedef float f32x4 __attribute__((ext_vector_type(4)));

static inline size_t align512(size_t x) { return (x + 511) & ~((size_t)511); }

// ---- zero cnt (rocclr fill was 44us in-graph; our kernel ~3us) ----------
__global__ void zero_kernel(int* __restrict__ p, int n) {
    int i = blockIdx.x * 256 + threadIdx.x;
    if (i < n) p[i] = 0;
}

// ---- fused: W1,W2 -> fp16 transposed [col][k]  ∥  degree histogram ------
__global__ __launch_bounds__(256) void prep_count(const float* __restrict__ W1,
                                                  const float* __restrict__ W2,
                                                  __half* __restrict__ W1t,
                                                  __half* __restrict__ W2t,
                                                  const int* __restrict__ dst,
                                                  int* __restrict__ cnt, int ne) {
    int b = blockIdx.x;
    if (b < 128) {
        const float* W = (b < 64) ? W1 : W2;
        __half* Wt = (b < 64) ? W1t : W2t;
        int gid = (b & 63) * 256 + threadIdx.x;      // 0..16383
        int c = gid >> 7, k = gid & 127;
        Wt[(size_t)c * FDIM + k] = __float2half(W[(size_t)k * FDIM + c]);
        return;
    }
    int base = ((b - 128) * 256 + threadIdx.x) * 4;
    if (base + 3 < ne) {
        int4 d = *(const int4*)(dst + base);
        atomicAdd(&cnt[d.x], 1);
        atomicAdd(&cnt[d.y], 1);
        atomicAdd(&cnt[d.z], 1);
        atomicAdd(&cnt[d.w], 1);
    } else {
        for (int i = base; i < ne; i++) atomicAdd(&cnt[dst[i]], 1);
    }
}

// ---- MFMA GEMM (out_fp16 = fp16(X) @ Wt^T) + optional CSR scatter -------
// 64 rows/block, 4 waves; wave w owns rows w*16..+15.
// A-frag: lane l = Xl[w*16+(l&15)][kk*32+(l>>4)*8..+8)  (LDS, pad 136)
// B-frag: lane l = Wt[c*16+(l&15)][kk*32+(l>>4)*8..+8)  (global, L2-hot)
// D (lane l, reg r -> row (l>>4)*4+r, col l&15) goes to LDS (Xl reused),
// then coalesced 32B/thread row stores. R12: direct 2B D-stores caused 3x
// write amplification (WRITE 37MB for 12.8MB logical) = the whole 56us.
__global__ __launch_bounds__(256) void gemm_mfma(const float* __restrict__ X,
                                                 const __half* __restrict__ Wt,
                                                 __half* __restrict__ out, int nrows,
                                                 int gemm_blocks,
                                                 const int* __restrict__ src,
                                                 const int* __restrict__ dstE,
                                                 const float* __restrict__ dinv,
                                                 int* __restrict__ cursor,
                                                 int2* __restrict__ csr_pack, int ne) {
    __shared__ __half Xl[64 * 136];   // X tile fp16, then reused as D staging
    if ((int)blockIdx.x >= gemm_blocks) {
        // ---- CSR scatter: 4 edges/thread ----
        int base = (((int)blockIdx.x - gemm_blocks) * 256 + threadIdx.x) * 4;
        if (base + 3 < ne) {
            int4 s4 = *(const int4*)(src + base);
            int4 d4 = *(const int4*)(dstE + base);
            int p0 = atomicAdd(&cursor[d4.x], 1);
            int p1 = atomicAdd(&cursor[d4.y], 1);
            int p2 = atomicAdd(&cursor[d4.z], 1);
            int p3 = atomicAdd(&cursor[d4.w], 1);
            float v0 = dinv[s4.x], v1 = dinv[s4.y], v2 = dinv[s4.z], v3 = dinv[s4.w];
            int2 q0; q0.x = s4.x; q0.y = __float_as_int(v0);
            int2 q1; q1.x = s4.y; q1.y = __float_as_int(v1);
            int2 q2; q2.x = s4.z; q2.y = __float_as_int(v2);
            int2 q3; q3.x = s4.w; q3.y = __float_as_int(v3);
            csr_pack[p0] = q0;
            csr_pack[p1] = q1;
            csr_pack[p2] = q2;
            csr_pack[p3] = q3;
        } else {
            for (int i = base; i < ne; i++) {
                int d = dstE[i], s = src[i];
                int pos = atomicAdd(&cursor[d], 1);
                int2 p;
                p.x = s;
                p.y = __float_as_int(dinv[s]);
                csr_pack[pos] = p;
            }
        }
        return;
    }
    int tid = threadIdx.x;
    int row0 = blockIdx.x * 64;

    // stage X tile fp32 -> fp16 LDS (rows clamped; clamp only affects rows
    // that are masked at the final store)
    for (int i = tid; i < 64 * 32; i += 256) {
        int r = i >> 5, c4 = i & 31;
        int rg = row0 + r;
        if (rg > nrows - 1) rg = nrows - 1;
        float4 v = *(const float4*)(X + (size_t)rg * FDIM + c4 * 4);
        union { __half2 h[2]; int2 i2; } u;
        u.h[0] = __floats2half2_rn(v.x, v.y);
        u.h[1] = __floats2half2_rn(v.z, v.w);
        *(int2*)(&Xl[r * 136 + c4 * 4]) = u.i2;
    }
    __syncthreads();

    int lane = tid & 63;
    int w = tid >> 6;                 // wave id 0..3
    int l15 = lane & 15;
    int kq = lane >> 4;               // k quarter 0..3

    f16x8 a[4];
    #pragma unroll
    for (int kk = 0; kk < 4; kk++)
        a[kk] = *(const f16x8*)(&Xl[(w * 16 + l15) * 136 + kk * 32 + kq * 8]);
    __syncthreads();                  // all A-frags read; Xl now D staging

    #pragma unroll
    for (int c = 0; c < 8; c++) {
        f32x4 acc = {0.f, 0.f, 0.f, 0.f};
        #pragma unroll
        for (int kk = 0; kk < 4; kk++) {
            f16x8 b = *(const f16x8*)(Wt + (size_t)(c * 16 + l15) * FDIM + kk * 32 + kq * 8);
            acc = __builtin_amdgcn_mfma_f32_16x16x32_f16(a[kk], b, acc, 0, 0, 0);
        }
        // D -> LDS (wave-private rows w*16..+15)
        #pragma unroll
        for (int r = 0; r < 4; r++)
            Xl[(w * 16 + kq * 4 + r) * 136 + c * 16 + l15] = __float2half(acc[r]);
    }
    __syncthreads();

    // coalesced store: 512 segments of 16 halfs (32B); 8 threads cover a row
    #pragma unroll
    for (int it = 0; it < 2; it++) {
        int i = it * 256 + tid;
        int r = i >> 3, seg = i & 7;
        int rowg = row0 + r;
        if (rowg < nrows) {
            int4 v0 = *(const int4*)(&Xl[r * 136 + seg * 16]);
            int4 v1 = *(const int4*)(&Xl[r * 136 + seg * 16 + 8]);
            int4* p = (int4*)(out + (size_t)rowg * FDIM + seg * 16);
            p[0] = v0; p[1] = v1;
        }
    }
}

// ---- Hierarchical exclusive scan ----------------------------------------
__global__ __launch_bounds__(256) void scan_block_sums(const int* __restrict__ cnt,
                                                       int* __restrict__ bsum, int n) {
    __shared__ int red[256];
    int tid = threadIdx.x;
    int idx = blockIdx.x * 256 + tid;
    red[tid] = (idx < n) ? cnt[idx] : 0;
    __syncthreads();
    for (int off = 128; off > 0; off >>= 1) {
        if (tid < off) red[tid] += red[tid + off];
        __syncthreads();
    }
    if (tid == 0) bsum[blockIdx.x] = red[0];
}

__global__ __launch_bounds__(1024) void scan_bsums(int* __restrict__ bsum, int nb) {
    __shared__ int sh[1024];
    int tid = threadIdx.x;
    int v = (tid < nb) ? bsum[tid] : 0;
    sh[tid] = v;
    __syncthreads();
    for (int off = 1; off < 1024; off <<= 1) {
        int t = (tid >= off) ? sh[tid - off] : 0;
        __syncthreads();
        sh[tid] += t;
        __syncthreads();
    }
    if (tid < nb) bsum[tid] = sh[tid] - v;   // exclusive
}

// also emits dinv = 1/sqrt(deg+1)
__global__ __launch_bounds__(256) void scan_final(const int* __restrict__ cnt,
                                                  const int* __restrict__ bsum,
                                                  int* __restrict__ rowptr,
                                                  int* __restrict__ cursor,
                                                  float* __restrict__ dinv, int n) {
    __shared__ int sh[256];
    int tid = threadIdx.x;
    int idx = blockIdx.x * 256 + tid;
    int c = (idx < n) ? cnt[idx] : 0;
    sh[tid] = c;
    __syncthreads();
    for (int off = 1; off < 256; off <<= 1) {
        int t = (tid >= off) ? sh[tid - off] : 0;
        __syncthreads();
        sh[tid] += t;
        __syncthreads();
    }
    if (idx < n) {
        int excl = sh[tid] - c + bsum[blockIdx.x];
        rowptr[idx] = excl;
        cursor[idx] = excl;
        dinv[idx] = 1.0f / sqrtf((float)(c + 1));
        if (idx == n - 1) rowptr[n] = excl + c;
    }
}

// ---- Aggregate + norm + bias + ELU --------------------------------------
// G is fp16 (row = 256 B); 16 nodes/block, 16 threads/node, 16 B float4/lane,
// edge loop unrolled x8. acc/output fp32.
__global__ __launch_bounds__(256) void agg_elu(const __half* __restrict__ G,
                                               const int* __restrict__ rowptr,
                                               const int2* __restrict__ csr_pack,
                                               const float* __restrict__ dinv,
                                               const float* __restrict__ bias,
                                               float* __restrict__ out, int n) {
    int node = blockIdx.x * 16 + (threadIdx.x >> 4);
    int c = threadIdx.x & 15;              // float4 (16 B) column
    if (node >= n) return;
    const float4* G4 = (const float4*)G;   // row stride = 16 float4s
    int beg = rowptr[node], end = rowptr[node + 1];
    float dn = dinv[node];

    float acc[8];
    {
        float4 sraw = G4[(size_t)node * 16 + c];
        __half2 h; float2 f;
        h = *(__half2*)&sraw.x; f = __half22float2(h); acc[0] = dn * f.x; acc[1] = dn * f.y;
        h = *(__half2*)&sraw.y; f = __half22float2(h); acc[2] = dn * f.x; acc[3] = dn * f.y;
        h = *(__half2*)&sraw.z; f = __half22float2(h); acc[4] = dn * f.x; acc[5] = dn * f.y;
        h = *(__half2*)&sraw.w; f = __half22float2(h); acc[6] = dn * f.x; acc[7] = dn * f.y;
    }

    #define ACC_EDGE(P, R)                                                   \
    {                                                                        \
        float d = __int_as_float(P.y);                                       \
        __half2 h; float2 f;                                                 \
        h = *(__half2*)&R.x; f = __half22float2(h);                          \
        acc[0] = fmaf(d, f.x, acc[0]); acc[1] = fmaf(d, f.y, acc[1]);        \
        h = *(__half2*)&R.y; f = __half22float2(h);                          \
        acc[2] = fmaf(d, f.x, acc[2]); acc[3] = fmaf(d, f.y, acc[3]);        \
        h = *(__half2*)&R.z; f = __half22float2(h);                          \
        acc[4] = fmaf(d, f.x, acc[4]); acc[5] = fmaf(d, f.y, acc[5]);        \
        h = *(__half2*)&R.w; f = __half22float2(h);                          \
        acc[6] = fmaf(d, f.x, acc[6]); acc[7] = fmaf(d, f.y, acc[7]);        \
    }

    int e = beg;
    for (; e + 7 < end; e += 8) {
        int2 p0 = csr_pack[e],     p1 = csr_pack[e + 1];
        int2 p2 = csr_pack[e + 2], p3 = csr_pack[e + 3];
        int2 p4 = csr_pack[e + 4], p5 = csr_pack[e + 5];
        int2 p6 = csr_pack[e + 6], p7 = csr_pack[e + 7];
        float4 r0 = G4[(size_t)p0.x * 16 + c];
        float4 r1 = G4[(size_t)p1.x * 16 + c];
        float4 r2 = G4[(size_t)p2.x * 16 + c];
        float4 r3 = G4[(size_t)p3.x * 16 + c];
        float4 r4 = G4[(size_t)p4.x * 16 + c];
        float4 r5 = G4[(size_t)p5.x * 16 + c];
        float4 r6 = G4[(size_t)p6.x * 16 + c];
        float4 r7 = G4[(size_t)p7.x * 16 + c];
        ACC_EDGE(p0, r0) ACC_EDGE(p1, r1) ACC_EDGE(p2, r2) ACC_EDGE(p3, r3)
        ACC_EDGE(p4, r4) ACC_EDGE(p5, r5) ACC_EDGE(p6, r6) ACC_EDGE(p7, r7)
    }
    for (; e < end; e++) {
        int2 p = csr_pack[e];
        float4 r = G4[(size_t)p.x * 16 + c];
        ACC_EDGE(p, r)
    }
    #undef ACC_EDGE

    const float4* b4 = (const float4*)bias;
    float4 blo = b4[2 * c], bhi = b4[2 * c + 1];
    float4 vlo, vhi;
    vlo.x = fmaf(dn, acc[0], blo.x); vlo.y = fmaf(dn, acc[1], blo.y);
    vlo.z = fmaf(dn, acc[2], blo.z); vlo.w = fmaf(dn, acc[3], blo.w);
    vhi.x = fmaf(dn, acc[4], bhi.x); vhi.y = fmaf(dn, acc[5], bhi.y);
    vhi.z = fmaf(dn, acc[6], bhi.z); vhi.w = fmaf(dn, acc[7], bhi.w);
    vlo.x = (vlo.x > 0.f) ? vlo.x : expm1f(vlo.x);
    vlo.y = (vlo.y > 0.f) ? vlo.y : expm1f(vlo.y);
    vlo.z = (vlo.z > 0.f) ? vlo.z : expm1f(vlo.z);
    vlo.w = (vlo.w > 0.f) ? vlo.w : expm1f(vlo.w);
    vhi.x = (vhi.x > 0.f) ? vhi.x : expm1f(vhi.x);
    vhi.y = (vhi.y > 0.f) ? vhi.y : expm1f(vhi.y);
    vhi.z = (vhi.z > 0.f) ? vhi.z : expm1f(vhi.z);
    vhi.w = (vhi.w > 0.f) ? vhi.w : expm1f(vhi.w);
    float4* o4 = (float4*)out;
    o4[(size_t)node * 32 + 2 * c] = vlo;
    o4[(size_t)node * 32 + 2 * c + 1] = vhi;
}

// ---- Global mean pool (contiguous nper-node graphs) ---------------------
__global__ __launch_bounds__(256) void pool_kernel(const float* __restrict__ H,
                                                   float* __restrict__ out,
                                                   int nper, int ngraphs) {
    __shared__ float tmp[128];
    int g = blockIdx.x;
    int f = threadIdx.x & 127;
    int half = threadIdx.x >> 7;
    if (g >= ngraphs) return;
    const float* base = H + (size_t)g * nper * FDIM;
    float acc = 0.f;
    for (int i = half; i < nper; i += 2) acc += base[(size_t)i * FDIM + f];
    if (half == 1) tmp[f] = acc;
    __syncthreads();
    if (half == 0) out[(size_t)g * FDIM + f] = (acc + tmp[f]) * (1.0f / (float)nper);
}

extern "C" void kernel_launch(void* const* d_in, const int* in_sizes, int n_in,
                              void* d_out, int out_size, void* d_ws, size_t ws_size,
                              hipStream_t stream) {
    const float* x  = (const float*)d_in[0];
    const float* W1 = (const float*)d_in[1];
    const float* b1 = (const float*)d_in[2];
    const float* W2 = (const float*)d_in[3];
    const float* b2 = (const float*)d_in[4];
    const int* edge_index = (const int*)d_in[5];
    float* out = (float*)d_out;

    int N = in_sizes[0] / FDIM;
    int E = in_sizes[5] / 2;
    int G = out_size / FDIM;
    int nper = N / G;
    const int* src = edge_index;
    const int* dst = edge_index + E;

    char* ws = (char*)d_ws;
    size_t off = 0;
    int* cnt = (int*)(ws + off);        off = align512(off + (size_t)N * 4);
    int* rowptr = (int*)(ws + off);     off = align512(off + (size_t)(N + 1) * 4);
    int* cursor = (int*)(ws + off);     off = align512(off + (size_t)N * 4);
    float* dinv = (float*)(ws + off);   off = align512(off + (size_t)N * 4);
    int* bsum = (int*)(ws + off);       off = align512(off + (size_t)1024 * 4);
    __half* W1t = (__half*)(ws + off);  off = align512(off + (size_t)FDIM * FDIM * 2);
    __half* W2t = (__half*)(ws + off);  off = align512(off + (size_t)FDIM * FDIM * 2);
    int2* csr_pack = (int2*)(ws + off); off = align512(off + (size_t)E * 8);
    __half* bufG = (__half*)(ws + off); off = align512(off + (size_t)N * FDIM * 2);
    float* bufB = (float*)(ws + off);   off = align512(off + (size_t)N * FDIM * 4);
    (void)ws_size;

    int nb = (N + 255) / 256;                    // scan blocks (<=1024)
    int gemm_grid = (N + 63) / 64;               // 782
    int agg_grid = (N + 15) / 16;
    int e4_grid = (E / 4 + 255) / 256;           // 782 (count & scatter)

    zero_kernel<<<nb, 256, 0, stream>>>(cnt, N);
    // W^T fp16 build overlapped with degree histogram
    prep_count<<<128 + e4_grid, 256, 0, stream>>>(W1, W2, W1t, W2t, dst, cnt, E);
    scan_block_sums<<<nb, 256, 0, stream>>>(cnt, bsum, N);
    scan_bsums<<<1, 1024, 0, stream>>>(bsum, nb);
    scan_final<<<nb, 256, 0, stream>>>(cnt, bsum, rowptr, cursor, dinv, N);

    // layer-1 MFMA GEMM overlapped with CSR scatter (independent until agg1)
    gemm_mfma<<<gemm_grid + e4_grid, 256, 0, stream>>>(
        x, W1t, bufG, N, gemm_grid, src, dst, dinv, cursor, csr_pack, E);

    agg_elu<<<agg_grid, 256, 0, stream>>>(bufG, rowptr, csr_pack, dinv, b1, bufB, N);
    // layer-2 MFMA GEMM (no scatter part)
    gemm_mfma<<<gemm_grid, 256, 0, stream>>>(
        bufB, W2t, bufG, N, gemm_grid, src, dst, dinv, cursor, csr_pack, 0);
    agg_elu<<<agg_grid, 256, 0, stream>>>(bufG, rowptr, csr_pack, dinv, b2, bufB, N);
    pool_kernel<<<G, 256, 0, stream>>>(bufB, out, nper, G);
}

// Round 14
// 167.118 us; speedup vs baseline: 1.5044x; 1.4271x over previous
//
#include <hip/hip_runtime.h>
#include <hip/hip_fp16.h>
#include <math.h>

#define FDIM 128
#define MAXDEG 64

typedef _Float16 f16x8 __attribute__((ext_vector_type(8)));
typedef float f32x4 __attribute__((ext_vector_type(4)));

static inline size_t align512(size_t x) { return (x + 511) & ~((size_t)511); }

// ---- prep: zero cnt + W1,W2 -> fp16 transposed [col][k] -----------------
__global__ __launch_bounds__(256) void prep_kernel(int* __restrict__ cnt, int n,
                                                   const float* __restrict__ W1,
                                                   const float* __restrict__ W2,
                                                   __half* __restrict__ W1t,
                                                   __half* __restrict__ W2t, int zb) {
    int b = blockIdx.x;
    if (b < zb) {
        int i = b * 256 + threadIdx.x;
        if (i < n) cnt[i] = 0;
        return;
    }
    int q = b - zb;                              // 0..127
    const float* W = (q < 64) ? W1 : W2;
    __half* Wt = (q < 64) ? W1t : W2t;
    int gid = (q & 63) * 256 + threadIdx.x;      // 0..16383
    int c = gid >> 7, k = gid & 127;
    Wt[(size_t)c * FDIM + k] = __float2half(W[(size_t)k * FDIM + c]);
}

// ---- MEGA: MFMA GEMM (bufG = fp16(X)@W1t^T)  ∥  edge-pass ---------------
// Edge-pass: ONE returning atomic per edge serves as count AND bucket slot:
//   k = atomicAdd(&cnt[d],1); bucket[d*64+k] = s.
// No prefix-scan CSR at all -> the entire build runs under gemm1 (R13: the
// serial count+scan chain was ~35us of unhidden critical path).
// GEMM: 64 rows/block, 4 waves, A from LDS (pad 136), B = Wt from L2,
// D staged through LDS for coalesced 32B row stores (R12: 2B stores = 3x WA).
__global__ __launch_bounds__(256) void gemm_edges(const float* __restrict__ X,
                                                  const __half* __restrict__ Wt,
                                                  __half* __restrict__ out, int nrows,
                                                  int gemm_blocks,
                                                  const int* __restrict__ src,
                                                  const int* __restrict__ dstE,
                                                  int* __restrict__ cnt,
                                                  int* __restrict__ bucket, int ne) {
    __shared__ __half Xl[64 * 136];
    if ((int)blockIdx.x >= gemm_blocks) {
        int base = (((int)blockIdx.x - gemm_blocks) * 256 + threadIdx.x) * 4;
        if (base + 3 < ne) {
            int4 s4 = *(const int4*)(src + base);
            int4 d4 = *(const int4*)(dstE + base);
            int k0 = atomicAdd(&cnt[d4.x], 1);
            int k1 = atomicAdd(&cnt[d4.y], 1);
            int k2 = atomicAdd(&cnt[d4.z], 1);
            int k3 = atomicAdd(&cnt[d4.w], 1);
            if (k0 < MAXDEG) bucket[(size_t)d4.x * MAXDEG + k0] = s4.x;
            if (k1 < MAXDEG) bucket[(size_t)d4.y * MAXDEG + k1] = s4.y;
            if (k2 < MAXDEG) bucket[(size_t)d4.z * MAXDEG + k2] = s4.z;
            if (k3 < MAXDEG) bucket[(size_t)d4.w * MAXDEG + k3] = s4.w;
        } else {
            for (int i = base; i < ne; i++) {
                int d = dstE[i], s = src[i];
                int k = atomicAdd(&cnt[d], 1);
                if (k < MAXDEG) bucket[(size_t)d * MAXDEG + k] = s;
            }
        }
        return;
    }
    int tid = threadIdx.x;
    int row0 = blockIdx.x * 64;

    for (int i = tid; i < 64 * 32; i += 256) {
        int r = i >> 5, c4 = i & 31;
        int rg = row0 + r;
        if (rg > nrows - 1) rg = nrows - 1;
        float4 v = *(const float4*)(X + (size_t)rg * FDIM + c4 * 4);
        union { __half2 h[2]; int2 i2; } u;
        u.h[0] = __floats2half2_rn(v.x, v.y);
        u.h[1] = __floats2half2_rn(v.z, v.w);
        *(int2*)(&Xl[r * 136 + c4 * 4]) = u.i2;
    }
    __syncthreads();

    int lane = tid & 63;
    int w = tid >> 6;
    int l15 = lane & 15;
    int kq = lane >> 4;

    f16x8 a[4];
    #pragma unroll
    for (int kk = 0; kk < 4; kk++)
        a[kk] = *(const f16x8*)(&Xl[(w * 16 + l15) * 136 + kk * 32 + kq * 8]);
    __syncthreads();                  // Xl becomes D staging

    #pragma unroll
    for (int c = 0; c < 8; c++) {
        f32x4 acc = {0.f, 0.f, 0.f, 0.f};
        #pragma unroll
        for (int kk = 0; kk < 4; kk++) {
            f16x8 b = *(const f16x8*)(Wt + (size_t)(c * 16 + l15) * FDIM + kk * 32 + kq * 8);
            acc = __builtin_amdgcn_mfma_f32_16x16x32_f16(a[kk], b, acc, 0, 0, 0);
        }
        #pragma unroll
        for (int r = 0; r < 4; r++)
            Xl[(w * 16 + kq * 4 + r) * 136 + c * 16 + l15] = __float2half(acc[r]);
    }
    __syncthreads();

    #pragma unroll
    for (int it = 0; it < 2; it++) {
        int i = it * 256 + tid;
        int r = i >> 3, seg = i & 7;
        int rowg = row0 + r;
        if (rowg < nrows) {
            int4 v0 = *(const int4*)(&Xl[r * 136 + seg * 16]);
            int4 v1 = *(const int4*)(&Xl[r * 136 + seg * 16 + 8]);
            int4* p = (int4*)(out + (size_t)rowg * FDIM + seg * 16);
            p[0] = v0; p[1] = v1;
        }
    }
}

// ---- dinv = 1/sqrt(deg+1) ------------------------------------------------
__global__ void dinv_kernel(const int* __restrict__ cnt, float* __restrict__ dinv, int n) {
    int i = blockIdx.x * 256 + threadIdx.x;
    if (i < n) dinv[i] = 1.0f / sqrtf((float)(cnt[i] + 1));
}

// shared edge-accumulate macro: s -> dinv[s] (L2-hot 200KB) + 16B row gather
#define ACC_EDGE(S, R)                                                   \
{                                                                        \
    float d = dinv[S];                                                   \
    __half2 h; float2 f;                                                 \
    h = *(__half2*)&R.x; f = __half22float2(h);                          \
    acc[0] = fmaf(d, f.x, acc[0]); acc[1] = fmaf(d, f.y, acc[1]);        \
    h = *(__half2*)&R.y; f = __half22float2(h);                          \
    acc[2] = fmaf(d, f.x, acc[2]); acc[3] = fmaf(d, f.y, acc[3]);        \
    h = *(__half2*)&R.z; f = __half22float2(h);                          \
    acc[4] = fmaf(d, f.x, acc[4]); acc[5] = fmaf(d, f.y, acc[5]);        \
    h = *(__half2*)&R.w; f = __half22float2(h);                          \
    acc[6] = fmaf(d, f.x, acc[6]); acc[7] = fmaf(d, f.y, acc[7]);        \
}

// ---- FUSED agg1 + gemm2: per 64-node tile ---------------------------------
// Phase A: aggregate 4 groups of 16 nodes (16 threads/node, 16B/lane),
//          ELU(dinv*(sum+self)+b1) -> fp16 row in Xl.
// Phase B: MFMA x W2t (identical core to gemm_edges), coalesced store.
// Kills bufB's 50MB round-trip + a launch gap.
__global__ __launch_bounds__(256) void agg_gemm(const __half* __restrict__ G,
                                                const int* __restrict__ bucket,
                                                const int* __restrict__ cnt,
                                                const float* __restrict__ dinv,
                                                const float* __restrict__ bias,
                                                const __half* __restrict__ Wt,
                                                __half* __restrict__ out, int nrows) {
    __shared__ __half Xl[64 * 136];
    int tid = threadIdx.x;
    int row0 = blockIdx.x * 64;
    const float4* G4 = (const float4*)G;

    int c = tid & 15;
    const float4* b4 = (const float4*)bias;
    float4 blo = b4[2 * c], bhi = b4[2 * c + 1];

    for (int g = 0; g < 4; g++) {
        int r = g * 16 + (tid >> 4);
        int node = row0 + r;
        if (node > nrows - 1) node = nrows - 1;     // clamp; masked at store
        int deg = cnt[node]; if (deg > MAXDEG) deg = MAXDEG;
        const int* bk = bucket + (size_t)node * MAXDEG;
        float dn = dinv[node];

        float acc[8];
        {
            float4 sraw = G4[(size_t)node * 16 + c];
            __half2 h; float2 f;
            h = *(__half2*)&sraw.x; f = __half22float2(h); acc[0] = dn * f.x; acc[1] = dn * f.y;
            h = *(__half2*)&sraw.y; f = __half22float2(h); acc[2] = dn * f.x; acc[3] = dn * f.y;
            h = *(__half2*)&sraw.z; f = __half22float2(h); acc[4] = dn * f.x; acc[5] = dn * f.y;
            h = *(__half2*)&sraw.w; f = __half22float2(h); acc[6] = dn * f.x; acc[7] = dn * f.y;
        }
        int e = 0;
        for (; e + 3 < deg; e += 4) {
            int s0 = bk[e], s1 = bk[e + 1], s2 = bk[e + 2], s3 = bk[e + 3];
            float4 r0 = G4[(size_t)s0 * 16 + c];
            float4 r1 = G4[(size_t)s1 * 16 + c];
            float4 r2 = G4[(size_t)s2 * 16 + c];
            float4 r3 = G4[(size_t)s3 * 16 + c];
            ACC_EDGE(s0, r0) ACC_EDGE(s1, r1) ACC_EDGE(s2, r2) ACC_EDGE(s3, r3)
        }
        for (; e < deg; e++) {
            int s = bk[e];
            float4 rr = G4[(size_t)s * 16 + c];
            ACC_EDGE(s, rr)
        }
        float v[8];
        v[0] = fmaf(dn, acc[0], blo.x); v[1] = fmaf(dn, acc[1], blo.y);
        v[2] = fmaf(dn, acc[2], blo.z); v[3] = fmaf(dn, acc[3], blo.w);
        v[4] = fmaf(dn, acc[4], bhi.x); v[5] = fmaf(dn, acc[5], bhi.y);
        v[6] = fmaf(dn, acc[6], bhi.z); v[7] = fmaf(dn, acc[7], bhi.w);
        #pragma unroll
        for (int j = 0; j < 8; j++) v[j] = (v[j] > 0.f) ? v[j] : expm1f(v[j]);
        union { __half2 h[4]; int4 i4; } u;
        u.h[0] = __floats2half2_rn(v[0], v[1]);
        u.h[1] = __floats2half2_rn(v[2], v[3]);
        u.h[2] = __floats2half2_rn(v[4], v[5]);
        u.h[3] = __floats2half2_rn(v[6], v[7]);
        *(int4*)(&Xl[r * 136 + c * 8]) = u.i4;
    }
    __syncthreads();

    // ---- phase B: MFMA x W2t ----
    int lane = tid & 63;
    int w = tid >> 6;
    int l15 = lane & 15;
    int kq = lane >> 4;

    f16x8 a[4];
    #pragma unroll
    for (int kk = 0; kk < 4; kk++)
        a[kk] = *(const f16x8*)(&Xl[(w * 16 + l15) * 136 + kk * 32 + kq * 8]);
    __syncthreads();

    #pragma unroll
    for (int cc = 0; cc < 8; cc++) {
        f32x4 acc2 = {0.f, 0.f, 0.f, 0.f};
        #pragma unroll
        for (int kk = 0; kk < 4; kk++) {
            f16x8 b = *(const f16x8*)(Wt + (size_t)(cc * 16 + l15) * FDIM + kk * 32 + kq * 8);
            acc2 = __builtin_amdgcn_mfma_f32_16x16x32_f16(a[kk], b, acc2, 0, 0, 0);
        }
        #pragma unroll
        for (int r = 0; r < 4; r++)
            Xl[(w * 16 + kq * 4 + r) * 136 + cc * 16 + l15] = __float2half(acc2[r]);
    }
    __syncthreads();

    #pragma unroll
    for (int it = 0; it < 2; it++) {
        int i = it * 256 + tid;
        int r = i >> 3, seg = i & 7;
        int rowg = row0 + r;
        if (rowg < nrows) {
            int4 v0 = *(const int4*)(&Xl[r * 136 + seg * 16]);
            int4 v1 = *(const int4*)(&Xl[r * 136 + seg * 16 + 8]);
            int4* p = (int4*)(out + (size_t)rowg * FDIM + seg * 16);
            p[0] = v0; p[1] = v1;
        }
    }
}

// ---- final agg2: bucket-CSR, fp16 G, fp32 out ----------------------------
__global__ __launch_bounds__(256) void agg_elu(const __half* __restrict__ G,
                                               const int* __restrict__ bucket,
                                               const int* __restrict__ cnt,
                                               const float* __restrict__ dinv,
                                               const float* __restrict__ bias,
                                               float* __restrict__ out, int n) {
    int node = blockIdx.x * 16 + (threadIdx.x >> 4);
    int c = threadIdx.x & 15;
    if (node >= n) return;
    const float4* G4 = (const float4*)G;
    int deg = cnt[node]; if (deg > MAXDEG) deg = MAXDEG;
    const int* bk = bucket + (size_t)node * MAXDEG;
    float dn = dinv[node];

    float acc[8];
    {
        float4 sraw = G4[(size_t)node * 16 + c];
        __half2 h; float2 f;
        h = *(__half2*)&sraw.x; f = __half22float2(h); acc[0] = dn * f.x; acc[1] = dn * f.y;
        h = *(__half2*)&sraw.y; f = __half22float2(h); acc[2] = dn * f.x; acc[3] = dn * f.y;
        h = *(__half2*)&sraw.z; f = __half22float2(h); acc[4] = dn * f.x; acc[5] = dn * f.y;
        h = *(__half2*)&sraw.w; f = __half22float2(h); acc[6] = dn * f.x; acc[7] = dn * f.y;
    }
    int e = 0;
    for (; e + 3 < deg; e += 4) {
        int s0 = bk[e], s1 = bk[e + 1], s2 = bk[e + 2], s3 = bk[e + 3];
        float4 r0 = G4[(size_t)s0 * 16 + c];
        float4 r1 = G4[(size_t)s1 * 16 + c];
        float4 r2 = G4[(size_t)s2 * 16 + c];
        float4 r3 = G4[(size_t)s3 * 16 + c];
        ACC_EDGE(s0, r0) ACC_EDGE(s1, r1) ACC_EDGE(s2, r2) ACC_EDGE(s3, r3)
    }
    for (; e < deg; e++) {
        int s = bk[e];
        float4 rr = G4[(size_t)s * 16 + c];
        ACC_EDGE(s, rr)
    }

    const float4* b4 = (const float4*)bias;
    float4 blo = b4[2 * c], bhi = b4[2 * c + 1];
    float4 vlo, vhi;
    vlo.x = fmaf(dn, acc[0], blo.x); vlo.y = fmaf(dn, acc[1], blo.y);
    vlo.z = fmaf(dn, acc[2], blo.z); vlo.w = fmaf(dn, acc[3], blo.w);
    vhi.x = fmaf(dn, acc[4], bhi.x); vhi.y = fmaf(dn, acc[5], bhi.y);
    vhi.z = fmaf(dn, acc[6], bhi.z); vhi.w = fmaf(dn, acc[7], bhi.w);
    vlo.x = (vlo.x > 0.f) ? vlo.x : expm1f(vlo.x);
    vlo.y = (vlo.y > 0.f) ? vlo.y : expm1f(vlo.y);
    vlo.z = (vlo.z > 0.f) ? vlo.z : expm1f(vlo.z);
    vlo.w = (vlo.w > 0.f) ? vlo.w : expm1f(vlo.w);
    vhi.x = (vhi.x > 0.f) ? vhi.x : expm1f(vhi.x);
    vhi.y = (vhi.y > 0.f) ? vhi.y : expm1f(vhi.y);
    vhi.z = (vhi.z > 0.f) ? vhi.z : expm1f(vhi.z);
    vhi.w = (vhi.w > 0.f) ? vhi.w : expm1f(vhi.w);
    float4* o4 = (float4*)out;
    o4[(size_t)node * 32 + 2 * c] = vlo;
    o4[(size_t)node * 32 + 2 * c + 1] = vhi;
}

// ---- Global mean pool (contiguous nper-node graphs) ---------------------
__global__ __launch_bounds__(256) void pool_kernel(const float* __restrict__ H,
                                                   float* __restrict__ out,
                                                   int nper, int ngraphs) {
    __shared__ float tmp[128];
    int g = blockIdx.x;
    int f = threadIdx.x & 127;
    int half = threadIdx.x >> 7;
    if (g >= ngraphs) return;
    const float* base = H + (size_t)g * nper * FDIM;
    float acc = 0.f;
    for (int i = half; i < nper; i += 2) acc += base[(size_t)i * FDIM + f];
    if (half == 1) tmp[f] = acc;
    __syncthreads();
    if (half == 0) out[(size_t)g * FDIM + f] = (acc + tmp[f]) * (1.0f / (float)nper);
}

extern "C" void kernel_launch(void* const* d_in, const int* in_sizes, int n_in,
                              void* d_out, int out_size, void* d_ws, size_t ws_size,
                              hipStream_t stream) {
    const float* x  = (const float*)d_in[0];
    const float* W1 = (const float*)d_in[1];
    const float* b1 = (const float*)d_in[2];
    const float* W2 = (const float*)d_in[3];
    const float* b2 = (const float*)d_in[4];
    const int* edge_index = (const int*)d_in[5];
    float* out = (float*)d_out;

    int N = in_sizes[0] / FDIM;
    int E = in_sizes[5] / 2;
    int G = out_size / FDIM;
    int nper = N / G;
    const int* src = edge_index;
    const int* dst = edge_index + E;

    char* ws = (char*)d_ws;
    size_t off = 0;
    int* cnt = (int*)(ws + off);        off = align512(off + (size_t)N * 4);
    float* dinv = (float*)(ws + off);   off = align512(off + (size_t)N * 4);
    __half* W1t = (__half*)(ws + off);  off = align512(off + (size_t)FDIM * FDIM * 2);
    __half* W2t = (__half*)(ws + off);  off = align512(off + (size_t)FDIM * FDIM * 2);
    int* bucket = (int*)(ws + off);     off = align512(off + (size_t)N * MAXDEG * 4);
    __half* bufG = (__half*)(ws + off); off = align512(off + (size_t)N * FDIM * 2);
    __half* bufH = (__half*)(ws + off); off = align512(off + (size_t)N * FDIM * 2);
    float* bufB = (float*)(ws + off);   off = align512(off + (size_t)N * FDIM * 4);
    (void)ws_size;

    int nb = (N + 255) / 256;
    int gemm_grid = (N + 63) / 64;               // 782
    int agg_grid = (N + 15) / 16;
    int e4_grid = (E / 4 + 255) / 256;           // 782

    // zero cnt + fp16 W^T build
    prep_kernel<<<nb + 128, 256, 0, stream>>>(cnt, N, W1, W2, W1t, W2t, nb);
    // MEGA: layer-1 GEMM ∥ full CSR-bucket build (count+scatter in one atomic)
    gemm_edges<<<gemm_grid + e4_grid, 256, 0, stream>>>(
        x, W1t, bufG, N, gemm_grid, src, dst, cnt, bucket, E);
    dinv_kernel<<<nb, 256, 0, stream>>>(cnt, dinv, N);
    // fused agg1 + layer-2 GEMM
    agg_gemm<<<gemm_grid, 256, 0, stream>>>(bufG, bucket, cnt, dinv, b1, W2t, bufH, N);
    // final agg2 + pool
    agg_elu<<<agg_grid, 256, 0, stream>>>(bufH, bucket, cnt, dinv, b2, bufB, N);
    pool_kernel<<<G, 256, 0, stream>>>(bufB, out, nper, G);
}

// Round 15
// 166.317 us; speedup vs baseline: 1.5117x; 1.0048x over previous
//
#include <hip/hip_runtime.h>
#include <hip/hip_fp16.h>
#include <math.h>

#define FDIM 128
#define MAXDEG 64

typedef _Float16 f16x8 __attribute__((ext_vector_type(8)));
typedef float f32x4 __attribute__((ext_vector_type(4)));

static inline size_t align512(size_t x) { return (x + 511) & ~((size_t)511); }

// ---- prep: zero cnt + W1,W2 -> fp16 transposed [col][k] -----------------
__global__ __launch_bounds__(256) void prep_kernel(int* __restrict__ cnt, int n,
                                                   const float* __restrict__ W1,
                                                   const float* __restrict__ W2,
                                                   __half* __restrict__ W1t,
                                                   __half* __restrict__ W2t, int zb) {
    int b = blockIdx.x;
    if (b < zb) {
        int i = b * 256 + threadIdx.x;
        if (i < n) cnt[i] = 0;
        return;
    }
    int q = b - zb;                              // 0..127
    const float* W = (q < 64) ? W1 : W2;
    __half* Wt = (q < 64) ? W1t : W2t;
    int gid = (q & 63) * 256 + threadIdx.x;      // 0..16383
    int c = gid >> 7, k = gid & 127;
    Wt[(size_t)c * FDIM + k] = __float2half(W[(size_t)k * FDIM + c]);
}

// ---- MEGA: MFMA GEMM (bufG = fp16(X)@W1t^T)  ∥  edge-pass ---------------
// Edge-pass: ONE returning atomic per edge = count AND bucket slot (no scan).
// GEMM: 64 rows/block, 4 waves, A from LDS (pad 136), B = Wt from L2,
// D staged through LDS for coalesced 32B row stores (R12: 2B stores = 3x WA).
__global__ __launch_bounds__(256) void gemm_edges(const float* __restrict__ X,
                                                  const __half* __restrict__ Wt,
                                                  __half* __restrict__ out, int nrows,
                                                  int gemm_blocks,
                                                  const int* __restrict__ src,
                                                  const int* __restrict__ dstE,
                                                  int* __restrict__ cnt,
                                                  int* __restrict__ bucket, int ne) {
    __shared__ __half Xl[64 * 136];
    if ((int)blockIdx.x >= gemm_blocks) {
        int base = (((int)blockIdx.x - gemm_blocks) * 256 + threadIdx.x) * 4;
        if (base + 3 < ne) {
            int4 s4 = *(const int4*)(src + base);
            int4 d4 = *(const int4*)(dstE + base);
            int k0 = atomicAdd(&cnt[d4.x], 1);
            int k1 = atomicAdd(&cnt[d4.y], 1);
            int k2 = atomicAdd(&cnt[d4.z], 1);
            int k3 = atomicAdd(&cnt[d4.w], 1);
            if (k0 < MAXDEG) bucket[(size_t)d4.x * MAXDEG + k0] = s4.x;
            if (k1 < MAXDEG) bucket[(size_t)d4.y * MAXDEG + k1] = s4.y;
            if (k2 < MAXDEG) bucket[(size_t)d4.z * MAXDEG + k2] = s4.z;
            if (k3 < MAXDEG) bucket[(size_t)d4.w * MAXDEG + k3] = s4.w;
        } else {
            for (int i = base; i < ne; i++) {
                int d = dstE[i], s = src[i];
                int k = atomicAdd(&cnt[d], 1);
                if (k < MAXDEG) bucket[(size_t)d * MAXDEG + k] = s;
            }
        }
        return;
    }
    int tid = threadIdx.x;
    int row0 = blockIdx.x * 64;

    for (int i = tid; i < 64 * 32; i += 256) {
        int r = i >> 5, c4 = i & 31;
        int rg = row0 + r;
        if (rg > nrows - 1) rg = nrows - 1;
        float4 v = *(const float4*)(X + (size_t)rg * FDIM + c4 * 4);
        union { __half2 h[2]; int2 i2; } u;
        u.h[0] = __floats2half2_rn(v.x, v.y);
        u.h[1] = __floats2half2_rn(v.z, v.w);
        *(int2*)(&Xl[r * 136 + c4 * 4]) = u.i2;
    }
    __syncthreads();

    int lane = tid & 63;
    int w = tid >> 6;
    int l15 = lane & 15;
    int kq = lane >> 4;

    f16x8 a[4];
    #pragma unroll
    for (int kk = 0; kk < 4; kk++)
        a[kk] = *(const f16x8*)(&Xl[(w * 16 + l15) * 136 + kk * 32 + kq * 8]);
    __syncthreads();                  // Xl becomes D staging

    #pragma unroll
    for (int c = 0; c < 8; c++) {
        f32x4 acc = {0.f, 0.f, 0.f, 0.f};
        #pragma unroll
        for (int kk = 0; kk < 4; kk++) {
            f16x8 b = *(const f16x8*)(Wt + (size_t)(c * 16 + l15) * FDIM + kk * 32 + kq * 8);
            acc = __builtin_amdgcn_mfma_f32_16x16x32_f16(a[kk], b, acc, 0, 0, 0);
        }
        #pragma unroll
        for (int r = 0; r < 4; r++)
            Xl[(w * 16 + kq * 4 + r) * 136 + c * 16 + l15] = __float2half(acc[r]);
    }
    __syncthreads();

    #pragma unroll
    for (int it = 0; it < 2; it++) {
        int i = it * 256 + tid;
        int r = i >> 3, seg = i & 7;
        int rowg = row0 + r;
        if (rowg < nrows) {
            int4 v0 = *(const int4*)(&Xl[r * 136 + seg * 16]);
            int4 v1 = *(const int4*)(&Xl[r * 136 + seg * 16 + 8]);
            int4* p = (int4*)(out + (size_t)rowg * FDIM + seg * 16);
            p[0] = v0; p[1] = v1;
        }
    }
}

// ---- dinv = 1/sqrt(deg+1) ------------------------------------------------
__global__ void dinv_kernel(const int* __restrict__ cnt, float* __restrict__ dinv, int n) {
    int i = blockIdx.x * 256 + threadIdx.x;
    if (i < n) dinv[i] = 1.0f / sqrtf((float)(cnt[i] + 1));
}

// shared edge-accumulate macro: s -> dinv[s] (L2-hot 200KB) + 16B row gather
#define ACC_EDGE(S, R)                                                   \
{                                                                        \
    float d = dinv[S];                                                   \
    __half2 h; float2 f;                                                 \
    h = *(__half2*)&R.x; f = __half22float2(h);                          \
    acc[0] = fmaf(d, f.x, acc[0]); acc[1] = fmaf(d, f.y, acc[1]);        \
    h = *(__half2*)&R.y; f = __half22float2(h);                          \
    acc[2] = fmaf(d, f.x, acc[2]); acc[3] = fmaf(d, f.y, acc[3]);        \
    h = *(__half2*)&R.z; f = __half22float2(h);                          \
    acc[4] = fmaf(d, f.x, acc[4]); acc[5] = fmaf(d, f.y, acc[5]);        \
    h = *(__half2*)&R.w; f = __half22float2(h);                          \
    acc[6] = fmaf(d, f.x, acc[6]); acc[7] = fmaf(d, f.y, acc[7]);        \
}

// ---- FUSED agg1 + gemm2: 32-node tiles ------------------------------------
// R14: 64-row tile => grid 782 = 3 blocks/CU, occupancy 23%, gather-starved.
// 32 rows/block: grid 1563 (6/CU), LDS 8.7 KB. MFMA split: wave w owns
// rows (w&1)*16..+15 x col-tiles (w>>1)*4..+3 (D regions disjoint).
__global__ __launch_bounds__(256) void agg_gemm(const __half* __restrict__ G,
                                                const int* __restrict__ bucket,
                                                const int* __restrict__ cnt,
                                                const float* __restrict__ dinv,
                                                const float* __restrict__ bias,
                                                const __half* __restrict__ Wt,
                                                __half* __restrict__ out, int nrows) {
    __shared__ __half Xl[32 * 136];
    int tid = threadIdx.x;
    int row0 = blockIdx.x * 32;
    const float4* G4 = (const float4*)G;

    int c = tid & 15;
    const float4* b4 = (const float4*)bias;
    float4 blo = b4[2 * c], bhi = b4[2 * c + 1];

    for (int g = 0; g < 2; g++) {
        int r = g * 16 + (tid >> 4);
        int node = row0 + r;
        if (node > nrows - 1) node = nrows - 1;     // clamp; masked at store
        int deg = cnt[node]; if (deg > MAXDEG) deg = MAXDEG;
        const int* bk = bucket + (size_t)node * MAXDEG;
        float dn = dinv[node];

        float acc[8];
        {
            float4 sraw = G4[(size_t)node * 16 + c];
            __half2 h; float2 f;
            h = *(__half2*)&sraw.x; f = __half22float2(h); acc[0] = dn * f.x; acc[1] = dn * f.y;
            h = *(__half2*)&sraw.y; f = __half22float2(h); acc[2] = dn * f.x; acc[3] = dn * f.y;
            h = *(__half2*)&sraw.z; f = __half22float2(h); acc[4] = dn * f.x; acc[5] = dn * f.y;
            h = *(__half2*)&sraw.w; f = __half22float2(h); acc[6] = dn * f.x; acc[7] = dn * f.y;
        }
        int e = 0;
        for (; e + 3 < deg; e += 4) {
            int s0 = bk[e], s1 = bk[e + 1], s2 = bk[e + 2], s3 = bk[e + 3];
            float4 r0 = G4[(size_t)s0 * 16 + c];
            float4 r1 = G4[(size_t)s1 * 16 + c];
            float4 r2 = G4[(size_t)s2 * 16 + c];
            float4 r3 = G4[(size_t)s3 * 16 + c];
            ACC_EDGE(s0, r0) ACC_EDGE(s1, r1) ACC_EDGE(s2, r2) ACC_EDGE(s3, r3)
        }
        for (; e < deg; e++) {
            int s = bk[e];
            float4 rr = G4[(size_t)s * 16 + c];
            ACC_EDGE(s, rr)
        }
        float v[8];
        v[0] = fmaf(dn, acc[0], blo.x); v[1] = fmaf(dn, acc[1], blo.y);
        v[2] = fmaf(dn, acc[2], blo.z); v[3] = fmaf(dn, acc[3], blo.w);
        v[4] = fmaf(dn, acc[4], bhi.x); v[5] = fmaf(dn, acc[5], bhi.y);
        v[6] = fmaf(dn, acc[6], bhi.z); v[7] = fmaf(dn, acc[7], bhi.w);
        #pragma unroll
        for (int j = 0; j < 8; j++) v[j] = (v[j] > 0.f) ? v[j] : expm1f(v[j]);
        union { __half2 h[4]; int4 i4; } u;
        u.h[0] = __floats2half2_rn(v[0], v[1]);
        u.h[1] = __floats2half2_rn(v[2], v[3]);
        u.h[2] = __floats2half2_rn(v[4], v[5]);
        u.h[3] = __floats2half2_rn(v[6], v[7]);
        *(int4*)(&Xl[r * 136 + c * 8]) = u.i4;
    }
    __syncthreads();

    // ---- phase B: MFMA x W2t ----
    int lane = tid & 63;
    int w = tid >> 6;
    int l15 = lane & 15;
    int kq = lane >> 4;
    int rb = (w & 1) * 16;            // row base for this wave
    int ctb = (w >> 1) * 4;           // col-tile base

    f16x8 a[4];
    #pragma unroll
    for (int kk = 0; kk < 4; kk++)
        a[kk] = *(const f16x8*)(&Xl[(rb + l15) * 136 + kk * 32 + kq * 8]);
    __syncthreads();

    #pragma unroll
    for (int cc = 0; cc < 4; cc++) {
        int ct = ctb + cc;
        f32x4 acc2 = {0.f, 0.f, 0.f, 0.f};
        #pragma unroll
        for (int kk = 0; kk < 4; kk++) {
            f16x8 b = *(const f16x8*)(Wt + (size_t)(ct * 16 + l15) * FDIM + kk * 32 + kq * 8);
            acc2 = __builtin_amdgcn_mfma_f32_16x16x32_f16(a[kk], b, acc2, 0, 0, 0);
        }
        #pragma unroll
        for (int r = 0; r < 4; r++)
            Xl[(rb + kq * 4 + r) * 136 + ct * 16 + l15] = __float2half(acc2[r]);
    }
    __syncthreads();

    // coalesced store: 32 rows x 8 segs of 16 halfs (32B) = 256 stores
    {
        int i = tid;
        int r = i >> 3, seg = i & 7;
        int rowg = row0 + r;
        if (rowg < nrows) {
            int4 v0 = *(const int4*)(&Xl[r * 136 + seg * 16]);
            int4 v1 = *(const int4*)(&Xl[r * 136 + seg * 16 + 8]);
            int4* p = (int4*)(out + (size_t)rowg * FDIM + seg * 16);
            p[0] = v0; p[1] = v1;
        }
    }
}

// ---- final agg2: bucket-CSR, fp16 G, fp32 out ----------------------------
__global__ __launch_bounds__(256) void agg_elu(const __half* __restrict__ G,
                                               const int* __restrict__ bucket,
                                               const int* __restrict__ cnt,
                                               const float* __restrict__ dinv,
                                               const float* __restrict__ bias,
                                               float* __restrict__ out, int n) {
    int node = blockIdx.x * 16 + (threadIdx.x >> 4);
    int c = threadIdx.x & 15;
    if (node >= n) return;
    const float4* G4 = (const float4*)G;
    int deg = cnt[node]; if (deg > MAXDEG) deg = MAXDEG;
    const int* bk = bucket + (size_t)node * MAXDEG;
    float dn = dinv[node];

    float acc[8];
    {
        float4 sraw = G4[(size_t)node * 16 + c];
        __half2 h; float2 f;
        h = *(__half2*)&sraw.x; f = __half22float2(h); acc[0] = dn * f.x; acc[1] = dn * f.y;
        h = *(__half2*)&sraw.y; f = __half22float2(h); acc[2] = dn * f.x; acc[3] = dn * f.y;
        h = *(__half2*)&sraw.z; f = __half22float2(h); acc[4] = dn * f.x; acc[5] = dn * f.y;
        h = *(__half2*)&sraw.w; f = __half22float2(h); acc[6] = dn * f.x; acc[7] = dn * f.y;
    }
    int e = 0;
    for (; e + 3 < deg; e += 4) {
        int s0 = bk[e], s1 = bk[e + 1], s2 = bk[e + 2], s3 = bk[e + 3];
        float4 r0 = G4[(size_t)s0 * 16 + c];
        float4 r1 = G4[(size_t)s1 * 16 + c];
        float4 r2 = G4[(size_t)s2 * 16 + c];
        float4 r3 = G4[(size_t)s3 * 16 + c];
        ACC_EDGE(s0, r0) ACC_EDGE(s1, r1) ACC_EDGE(s2, r2) ACC_EDGE(s3, r3)
    }
    for (; e < deg; e++) {
        int s = bk[e];
        float4 rr = G4[(size_t)s * 16 + c];
        ACC_EDGE(s, rr)
    }

    const float4* b4 = (const float4*)bias;
    float4 blo = b4[2 * c], bhi = b4[2 * c + 1];
    float4 vlo, vhi;
    vlo.x = fmaf(dn, acc[0], blo.x); vlo.y = fmaf(dn, acc[1], blo.y);
    vlo.z = fmaf(dn, acc[2], blo.z); vlo.w = fmaf(dn, acc[3], blo.w);
    vhi.x = fmaf(dn, acc[4], bhi.x); vhi.y = fmaf(dn, acc[5], bhi.y);
    vhi.z = fmaf(dn, acc[6], bhi.z); vhi.w = fmaf(dn, acc[7], bhi.w);
    vlo.x = (vlo.x > 0.f) ? vlo.x : expm1f(vlo.x);
    vlo.y = (vlo.y > 0.f) ? vlo.y : expm1f(vlo.y);
    vlo.z = (vlo.z > 0.f) ? vlo.z : expm1f(vlo.z);
    vlo.w = (vlo.w > 0.f) ? vlo.w : expm1f(vlo.w);
    vhi.x = (vhi.x > 0.f) ? vhi.x : expm1f(vhi.x);
    vhi.y = (vhi.y > 0.f) ? vhi.y : expm1f(vhi.y);
    vhi.z = (vhi.z > 0.f) ? vhi.z : expm1f(vhi.z);
    vhi.w = (vhi.w > 0.f) ? vhi.w : expm1f(vhi.w);
    float4* o4 = (float4*)out;
    o4[(size_t)node * 32 + 2 * c] = vlo;
    o4[(size_t)node * 32 + 2 * c + 1] = vhi;
}

// ---- Global mean pool (contiguous nper-node graphs) ---------------------
__global__ __launch_bounds__(256) void pool_kernel(const float* __restrict__ H,
                                                   float* __restrict__ out,
                                                   int nper, int ngraphs) {
    __shared__ float tmp[128];
    int g = blockIdx.x;
    int f = threadIdx.x & 127;
    int half = threadIdx.x >> 7;
    if (g >= ngraphs) return;
    const float* base = H + (size_t)g * nper * FDIM;
    float acc = 0.f;
    for (int i = half; i < nper; i += 2) acc += base[(size_t)i * FDIM + f];
    if (half == 1) tmp[f] = acc;
    __syncthreads();
    if (half == 0) out[(size_t)g * FDIM + f] = (acc + tmp[f]) * (1.0f / (float)nper);
}

extern "C" void kernel_launch(void* const* d_in, const int* in_sizes, int n_in,
                              void* d_out, int out_size, void* d_ws, size_t ws_size,
                              hipStream_t stream) {
    const float* x  = (const float*)d_in[0];
    const float* W1 = (const float*)d_in[1];
    const float* b1 = (const float*)d_in[2];
    const float* W2 = (const float*)d_in[3];
    const float* b2 = (const float*)d_in[4];
    const int* edge_index = (const int*)d_in[5];
    float* out = (float*)d_out;

    int N = in_sizes[0] / FDIM;
    int E = in_sizes[5] / 2;
    int G = out_size / FDIM;
    int nper = N / G;
    const int* src = edge_index;
    const int* dst = edge_index + E;

    char* ws = (char*)d_ws;
    size_t off = 0;
    int* cnt = (int*)(ws + off);        off = align512(off + (size_t)N * 4);
    float* dinv = (float*)(ws + off);   off = align512(off + (size_t)N * 4);
    __half* W1t = (__half*)(ws + off);  off = align512(off + (size_t)FDIM * FDIM * 2);
    __half* W2t = (__half*)(ws + off);  off = align512(off + (size_t)FDIM * FDIM * 2);
    int* bucket = (int*)(ws + off);     off = align512(off + (size_t)N * MAXDEG * 4);
    __half* bufG = (__half*)(ws + off); off = align512(off + (size_t)N * FDIM * 2);
    __half* bufH = (__half*)(ws + off); off = align512(off + (size_t)N * FDIM * 2);
    float* bufB = (float*)(ws + off);   off = align512(off + (size_t)N * FDIM * 4);
    (void)ws_size;

    int nb = (N + 255) / 256;
    int gemm_grid = (N + 63) / 64;               // 782
    int ag_grid = (N + 31) / 32;                 // 1563
    int agg_grid = (N + 15) / 16;
    int e4_grid = (E / 4 + 255) / 256;           // 782

    // zero cnt + fp16 W^T build
    prep_kernel<<<nb + 128, 256, 0, stream>>>(cnt, N, W1, W2, W1t, W2t, nb);
    // MEGA: layer-1 GEMM ∥ full CSR-bucket build (count+scatter in one atomic)
    gemm_edges<<<gemm_grid + e4_grid, 256, 0, stream>>>(
        x, W1t, bufG, N, gemm_grid, src, dst, cnt, bucket, E);
    dinv_kernel<<<nb, 256, 0, stream>>>(cnt, dinv, N);
    // fused agg1 + layer-2 GEMM (32-node tiles)
    agg_gemm<<<ag_grid, 256, 0, stream>>>(bufG, bucket, cnt, dinv, b1, W2t, bufH, N);
    // final agg2 + pool
    agg_elu<<<agg_grid, 256, 0, stream>>>(bufH, bucket, cnt, dinv, b2, bufB, N);
    pool_kernel<<<G, 256, 0, stream>>>(bufB, out, nper, G);
}

// Round 16
// 164.444 us; speedup vs baseline: 1.5289x; 1.0114x over previous
//
#include <hip/hip_runtime.h>
#include <hip/hip_fp16.h>
#include <math.h>

#define FDIM 128
#define MAXDEG 64

typedef _Float16 f16x8 __attribute__((ext_vector_type(8)));
typedef float f32x4 __attribute__((ext_vector_type(4)));

static inline size_t align512(size_t x) { return (x + 511) & ~((size_t)511); }

// ---- prep: zero cnt + W1,W2 -> fp16 transposed [col][k] -----------------
__global__ __launch_bounds__(256) void prep_kernel(int* __restrict__ cnt, int n,
                                                   const float* __restrict__ W1,
                                                   const float* __restrict__ W2,
                                                   __half* __restrict__ W1t,
                                                   __half* __restrict__ W2t, int zb) {
    int b = blockIdx.x;
    if (b < zb) {
        int i = b * 256 + threadIdx.x;
        if (i < n) cnt[i] = 0;
        return;
    }
    int q = b - zb;                              // 0..127
    const float* W = (q < 64) ? W1 : W2;
    __half* Wt = (q < 64) ? W1t : W2t;
    int gid = (q & 63) * 256 + threadIdx.x;      // 0..16383
    int c = gid >> 7, k = gid & 127;
    Wt[(size_t)c * FDIM + k] = __float2half(W[(size_t)k * FDIM + c]);
}

// ---- MEGA: MFMA GEMM (bufG = fp16(X)@W1t^T)  ∥  edge-pass ---------------
// Edge-pass: ONE returning atomic per edge = count AND bucket slot (no scan).
// GEMM: 64 rows/block, 4 waves, A from LDS (pad 136), B = Wt from L2,
// D staged through LDS for coalesced 32B row stores (R12: 2B stores = 3x WA).
__global__ __launch_bounds__(256) void gemm_edges(const float* __restrict__ X,
                                                  const __half* __restrict__ Wt,
                                                  __half* __restrict__ out, int nrows,
                                                  int gemm_blocks,
                                                  const int* __restrict__ src,
                                                  const int* __restrict__ dstE,
                                                  int* __restrict__ cnt,
                                                  int* __restrict__ bucket, int ne) {
    __shared__ __half Xl[64 * 136];
    if ((int)blockIdx.x >= gemm_blocks) {
        int base = (((int)blockIdx.x - gemm_blocks) * 256 + threadIdx.x) * 4;
        if (base + 3 < ne) {
            int4 s4 = *(const int4*)(src + base);
            int4 d4 = *(const int4*)(dstE + base);
            int k0 = atomicAdd(&cnt[d4.x], 1);
            int k1 = atomicAdd(&cnt[d4.y], 1);
            int k2 = atomicAdd(&cnt[d4.z], 1);
            int k3 = atomicAdd(&cnt[d4.w], 1);
            if (k0 < MAXDEG) bucket[(size_t)d4.x * MAXDEG + k0] = s4.x;
            if (k1 < MAXDEG) bucket[(size_t)d4.y * MAXDEG + k1] = s4.y;
            if (k2 < MAXDEG) bucket[(size_t)d4.z * MAXDEG + k2] = s4.z;
            if (k3 < MAXDEG) bucket[(size_t)d4.w * MAXDEG + k3] = s4.w;
        } else {
            for (int i = base; i < ne; i++) {
                int d = dstE[i], s = src[i];
                int k = atomicAdd(&cnt[d], 1);
                if (k < MAXDEG) bucket[(size_t)d * MAXDEG + k] = s;
            }
        }
        return;
    }
    int tid = threadIdx.x;
    int row0 = blockIdx.x * 64;

    for (int i = tid; i < 64 * 32; i += 256) {
        int r = i >> 5, c4 = i & 31;
        int rg = row0 + r;
        if (rg > nrows - 1) rg = nrows - 1;
        float4 v = *(const float4*)(X + (size_t)rg * FDIM + c4 * 4);
        union { __half2 h[2]; int2 i2; } u;
        u.h[0] = __floats2half2_rn(v.x, v.y);
        u.h[1] = __floats2half2_rn(v.z, v.w);
        *(int2*)(&Xl[r * 136 + c4 * 4]) = u.i2;
    }
    __syncthreads();

    int lane = tid & 63;
    int w = tid >> 6;
    int l15 = lane & 15;
    int kq = lane >> 4;

    f16x8 a[4];
    #pragma unroll
    for (int kk = 0; kk < 4; kk++)
        a[kk] = *(const f16x8*)(&Xl[(w * 16 + l15) * 136 + kk * 32 + kq * 8]);
    __syncthreads();                  // Xl becomes D staging

    #pragma unroll
    for (int c = 0; c < 8; c++) {
        f32x4 acc = {0.f, 0.f, 0.f, 0.f};
        #pragma unroll
        for (int kk = 0; kk < 4; kk++) {
            f16x8 b = *(const f16x8*)(Wt + (size_t)(c * 16 + l15) * FDIM + kk * 32 + kq * 8);
            acc = __builtin_amdgcn_mfma_f32_16x16x32_f16(a[kk], b, acc, 0, 0, 0);
        }
        #pragma unroll
        for (int r = 0; r < 4; r++)
            Xl[(w * 16 + kq * 4 + r) * 136 + c * 16 + l15] = __float2half(acc[r]);
    }
    __syncthreads();

    #pragma unroll
    for (int it = 0; it < 2; it++) {
        int i = it * 256 + tid;
        int r = i >> 3, seg = i & 7;
        int rowg = row0 + r;
        if (rowg < nrows) {
            int4 v0 = *(const int4*)(&Xl[r * 136 + seg * 16]);
            int4 v1 = *(const int4*)(&Xl[r * 136 + seg * 16 + 8]);
            int4* p = (int4*)(out + (size_t)rowg * FDIM + seg * 16);
            p[0] = v0; p[1] = v1;
        }
    }
}

// ---- scale+dinv: dinv[i]=1/sqrt(deg+1); bufG[i,:] *= dinv[i] in place ----
// Removes the per-edge dinv[s] random gather from BOTH agg loops (R15: agg
// at throughput floor -> cut requests, not parallelism).
__global__ __launch_bounds__(256) void scale_dinv(const int* __restrict__ cnt,
                                                  float* __restrict__ dinv,
                                                  __half* __restrict__ G, int n) {
    int row = blockIdx.x * 4 + (threadIdx.x >> 6);
    int c = threadIdx.x & 63;
    if (row >= n) return;
    float dv = 1.0f / sqrtf((float)(cnt[row] + 1));
    if (c == 0) dinv[row] = dv;
    __half2* p = (__half2*)(G + (size_t)row * FDIM) + c;
    float2 f = __half22float2(*p);
    *p = __floats2half2_rn(f.x * dv, f.y * dv);
}

// pure row-sum accumulate (rows pre-scaled by dinv[src])
#define ACC_ROW(R)                                                       \
{                                                                        \
    __half2 h; float2 f;                                                 \
    h = *(__half2*)&R.x; f = __half22float2(h); acc[0] += f.x; acc[1] += f.y; \
    h = *(__half2*)&R.y; f = __half22float2(h); acc[2] += f.x; acc[3] += f.y; \
    h = *(__half2*)&R.z; f = __half22float2(h); acc[4] += f.x; acc[5] += f.y; \
    h = *(__half2*)&R.w; f = __half22float2(h); acc[6] += f.x; acc[7] += f.y; \
}

// ---- FUSED agg1 + gemm2: 32-node tiles ------------------------------------
// Phase A: 2 groups of 16 nodes; acc = sum of pre-scaled rows (unroll 8);
//          ELU(dinv_d*acc + b1) -> fp16 row in Xl.
// Phase B: MFMA x W2t; D scaled by dinv[row] at store (pre-scales bufH for
//          agg2's pure row-sum). Wave w: rows (w&1)*16..+15, col-tiles (w>>1)*4..+3.
__global__ __launch_bounds__(256) void agg_gemm(const __half* __restrict__ G,
                                                const int* __restrict__ bucket,
                                                const int* __restrict__ cnt,
                                                const float* __restrict__ dinv,
                                                const float* __restrict__ bias,
                                                const __half* __restrict__ Wt,
                                                __half* __restrict__ out, int nrows) {
    __shared__ __half Xl[32 * 136];
    int tid = threadIdx.x;
    int row0 = blockIdx.x * 32;
    const float4* G4 = (const float4*)G;

    int c = tid & 15;
    const float4* b4 = (const float4*)bias;
    float4 blo = b4[2 * c], bhi = b4[2 * c + 1];

    for (int g = 0; g < 2; g++) {
        int r = g * 16 + (tid >> 4);
        int node = row0 + r;
        if (node > nrows - 1) node = nrows - 1;     // clamp; masked at store
        int deg = cnt[node]; if (deg > MAXDEG) deg = MAXDEG;
        const int* bk = bucket + (size_t)node * MAXDEG;
        float dn = dinv[node];

        float acc[8];
        {
            float4 sraw = G4[(size_t)node * 16 + c];   // self row (pre-scaled)
            __half2 h; float2 f;
            h = *(__half2*)&sraw.x; f = __half22float2(h); acc[0] = f.x; acc[1] = f.y;
            h = *(__half2*)&sraw.y; f = __half22float2(h); acc[2] = f.x; acc[3] = f.y;
            h = *(__half2*)&sraw.z; f = __half22float2(h); acc[4] = f.x; acc[5] = f.y;
            h = *(__half2*)&sraw.w; f = __half22float2(h); acc[6] = f.x; acc[7] = f.y;
        }
        int e = 0;
        for (; e + 7 < deg; e += 8) {
            int4 i0 = *(const int4*)(bk + e);
            int4 i1 = *(const int4*)(bk + e + 4);
            float4 r0 = G4[(size_t)i0.x * 16 + c];
            float4 r1 = G4[(size_t)i0.y * 16 + c];
            float4 r2 = G4[(size_t)i0.z * 16 + c];
            float4 r3 = G4[(size_t)i0.w * 16 + c];
            float4 r4 = G4[(size_t)i1.x * 16 + c];
            float4 r5 = G4[(size_t)i1.y * 16 + c];
            float4 r6 = G4[(size_t)i1.z * 16 + c];
            float4 r7 = G4[(size_t)i1.w * 16 + c];
            ACC_ROW(r0) ACC_ROW(r1) ACC_ROW(r2) ACC_ROW(r3)
            ACC_ROW(r4) ACC_ROW(r5) ACC_ROW(r6) ACC_ROW(r7)
        }
        for (; e < deg; e++) {
            int s = bk[e];
            float4 rr = G4[(size_t)s * 16 + c];
            ACC_ROW(rr)
        }
        float v[8];
        v[0] = fmaf(dn, acc[0], blo.x); v[1] = fmaf(dn, acc[1], blo.y);
        v[2] = fmaf(dn, acc[2], blo.z); v[3] = fmaf(dn, acc[3], blo.w);
        v[4] = fmaf(dn, acc[4], bhi.x); v[5] = fmaf(dn, acc[5], bhi.y);
        v[6] = fmaf(dn, acc[6], bhi.z); v[7] = fmaf(dn, acc[7], bhi.w);
        #pragma unroll
        for (int j = 0; j < 8; j++) v[j] = (v[j] > 0.f) ? v[j] : expm1f(v[j]);
        union { __half2 h[4]; int4 i4; } u;
        u.h[0] = __floats2half2_rn(v[0], v[1]);
        u.h[1] = __floats2half2_rn(v[2], v[3]);
        u.h[2] = __floats2half2_rn(v[4], v[5]);
        u.h[3] = __floats2half2_rn(v[6], v[7]);
        *(int4*)(&Xl[r * 136 + c * 8]) = u.i4;
    }
    __syncthreads();

    // ---- phase B: MFMA x W2t, D pre-scaled by dinv[row] ----
    int lane = tid & 63;
    int w = tid >> 6;
    int l15 = lane & 15;
    int kq = lane >> 4;
    int rb = (w & 1) * 16;            // row base for this wave
    int ctb = (w >> 1) * 4;           // col-tile base

    f16x8 a[4];
    #pragma unroll
    for (int kk = 0; kk < 4; kk++)
        a[kk] = *(const f16x8*)(&Xl[(rb + l15) * 136 + kk * 32 + kq * 8]);
    __syncthreads();

    float dsc[4];
    #pragma unroll
    for (int r = 0; r < 4; r++) {
        int rowg = row0 + rb + kq * 4 + r;
        dsc[r] = dinv[(rowg < nrows) ? rowg : (nrows - 1)];
    }

    #pragma unroll
    for (int cc = 0; cc < 4; cc++) {
        int ct = ctb + cc;
        f32x4 acc2 = {0.f, 0.f, 0.f, 0.f};
        #pragma unroll
        for (int kk = 0; kk < 4; kk++) {
            f16x8 b = *(const f16x8*)(Wt + (size_t)(ct * 16 + l15) * FDIM + kk * 32 + kq * 8);
            acc2 = __builtin_amdgcn_mfma_f32_16x16x32_f16(a[kk], b, acc2, 0, 0, 0);
        }
        #pragma unroll
        for (int r = 0; r < 4; r++)
            Xl[(rb + kq * 4 + r) * 136 + ct * 16 + l15] = __float2half(acc2[r] * dsc[r]);
    }
    __syncthreads();

    {
        int i = tid;
        int r = i >> 3, seg = i & 7;
        int rowg = row0 + r;
        if (rowg < nrows) {
            int4 v0 = *(const int4*)(&Xl[r * 136 + seg * 16]);
            int4 v1 = *(const int4*)(&Xl[r * 136 + seg * 16 + 8]);
            int4* p = (int4*)(out + (size_t)rowg * FDIM + seg * 16);
            p[0] = v0; p[1] = v1;
        }
    }
}

// ---- final agg2: pre-scaled rows, fp16 in, fp16 out ----------------------
__global__ __launch_bounds__(256) void agg_elu(const __half* __restrict__ G,
                                               const int* __restrict__ bucket,
                                               const int* __restrict__ cnt,
                                               const float* __restrict__ dinv,
                                               const float* __restrict__ bias,
                                               __half* __restrict__ out, int n) {
    int node = blockIdx.x * 16 + (threadIdx.x >> 4);
    int c = threadIdx.x & 15;
    if (node >= n) return;
    const float4* G4 = (const float4*)G;
    int deg = cnt[node]; if (deg > MAXDEG) deg = MAXDEG;
    const int* bk = bucket + (size_t)node * MAXDEG;
    float dn = dinv[node];

    float acc[8];
    {
        float4 sraw = G4[(size_t)node * 16 + c];
        __half2 h; float2 f;
        h = *(__half2*)&sraw.x; f = __half22float2(h); acc[0] = f.x; acc[1] = f.y;
        h = *(__half2*)&sraw.y; f = __half22float2(h); acc[2] = f.x; acc[3] = f.y;
        h = *(__half2*)&sraw.z; f = __half22float2(h); acc[4] = f.x; acc[5] = f.y;
        h = *(__half2*)&sraw.w; f = __half22float2(h); acc[6] = f.x; acc[7] = f.y;
    }
    int e = 0;
    for (; e + 7 < deg; e += 8) {
        int4 i0 = *(const int4*)(bk + e);
        int4 i1 = *(const int4*)(bk + e + 4);
        float4 r0 = G4[(size_t)i0.x * 16 + c];
        float4 r1 = G4[(size_t)i0.y * 16 + c];
        float4 r2 = G4[(size_t)i0.z * 16 + c];
        float4 r3 = G4[(size_t)i0.w * 16 + c];
        float4 r4 = G4[(size_t)i1.x * 16 + c];
        float4 r5 = G4[(size_t)i1.y * 16 + c];
        float4 r6 = G4[(size_t)i1.z * 16 + c];
        float4 r7 = G4[(size_t)i1.w * 16 + c];
        ACC_ROW(r0) ACC_ROW(r1) ACC_ROW(r2) ACC_ROW(r3)
        ACC_ROW(r4) ACC_ROW(r5) ACC_ROW(r6) ACC_ROW(r7)
    }
    for (; e < deg; e++) {
        int s = bk[e];
        float4 rr = G4[(size_t)s * 16 + c];
        ACC_ROW(rr)
    }

    const float4* b4 = (const float4*)bias;
    float4 blo = b4[2 * c], bhi = b4[2 * c + 1];
    float v[8];
    v[0] = fmaf(dn, acc[0], blo.x); v[1] = fmaf(dn, acc[1], blo.y);
    v[2] = fmaf(dn, acc[2], blo.z); v[3] = fmaf(dn, acc[3], blo.w);
    v[4] = fmaf(dn, acc[4], bhi.x); v[5] = fmaf(dn, acc[5], bhi.y);
    v[6] = fmaf(dn, acc[6], bhi.z); v[7] = fmaf(dn, acc[7], bhi.w);
    #pragma unroll
    for (int j = 0; j < 8; j++) v[j] = (v[j] > 0.f) ? v[j] : expm1f(v[j]);
    union { __half2 h[4]; int4 i4; } u;
    u.h[0] = __floats2half2_rn(v[0], v[1]);
    u.h[1] = __floats2half2_rn(v[2], v[3]);
    u.h[2] = __floats2half2_rn(v[4], v[5]);
    u.h[3] = __floats2half2_rn(v[6], v[7]);
    ((int4*)(out + (size_t)node * FDIM))[c] = u.i4;
}

// ---- Global mean pool (fp16 input, contiguous nper-node graphs) ----------
__global__ __launch_bounds__(256) void pool_kernel(const __half* __restrict__ H,
                                                   float* __restrict__ out,
                                                   int nper, int ngraphs) {
    __shared__ float2 tmp[4][64];
    int g = blockIdx.x;
    int cp = threadIdx.x & 63;       // half2 column pair
    int q = threadIdx.x >> 6;        // row quarter
    if (g >= ngraphs) return;
    const __half2* base = (const __half2*)(H + (size_t)g * nper * FDIM) + cp;
    float2 acc = make_float2(0.f, 0.f);
    for (int i = q; i < nper; i += 4) {
        float2 f = __half22float2(base[(size_t)i * 64]);
        acc.x += f.x; acc.y += f.y;
    }
    tmp[q][cp] = acc;
    __syncthreads();
    if (q == 0) {
        float2 a = tmp[0][cp], b = tmp[1][cp], c2 = tmp[2][cp], d = tmp[3][cp];
        float inv = 1.0f / (float)nper;
        out[(size_t)g * FDIM + cp * 2]     = (a.x + b.x + c2.x + d.x) * inv;
        out[(size_t)g * FDIM + cp * 2 + 1] = (a.y + b.y + c2.y + d.y) * inv;
    }
}

extern "C" void kernel_launch(void* const* d_in, const int* in_sizes, int n_in,
                              void* d_out, int out_size, void* d_ws, size_t ws_size,
                              hipStream_t stream) {
    const float* x  = (const float*)d_in[0];
    const float* W1 = (const float*)d_in[1];
    const float* b1 = (const float*)d_in[2];
    const float* W2 = (const float*)d_in[3];
    const float* b2 = (const float*)d_in[4];
    const int* edge_index = (const int*)d_in[5];
    float* out = (float*)d_out;

    int N = in_sizes[0] / FDIM;
    int E = in_sizes[5] / 2;
    int G = out_size / FDIM;
    int nper = N / G;
    const int* src = edge_index;
    const int* dst = edge_index + E;

    char* ws = (char*)d_ws;
    size_t off = 0;
    int* cnt = (int*)(ws + off);         off = align512(off + (size_t)N * 4);
    float* dinv = (float*)(ws + off);    off = align512(off + (size_t)N * 4);
    __half* W1t = (__half*)(ws + off);   off = align512(off + (size_t)FDIM * FDIM * 2);
    __half* W2t = (__half*)(ws + off);   off = align512(off + (size_t)FDIM * FDIM * 2);
    int* bucket = (int*)(ws + off);      off = align512(off + (size_t)N * MAXDEG * 4);
    __half* bufG = (__half*)(ws + off);  off = align512(off + (size_t)N * FDIM * 2);
    __half* bufH = (__half*)(ws + off);  off = align512(off + (size_t)N * FDIM * 2);
    __half* bufBh = (__half*)(ws + off); off = align512(off + (size_t)N * FDIM * 2);
    (void)ws_size;

    int nb = (N + 255) / 256;
    int gemm_grid = (N + 63) / 64;               // 782
    int ag_grid = (N + 31) / 32;                 // 1563
    int agg_grid = (N + 15) / 16;
    int e4_grid = (E / 4 + 255) / 256;           // 782

    // zero cnt + fp16 W^T build
    prep_kernel<<<nb + 128, 256, 0, stream>>>(cnt, N, W1, W2, W1t, W2t, nb);
    // MEGA: layer-1 GEMM ∥ full CSR-bucket build (count+scatter in one atomic)
    gemm_edges<<<gemm_grid + e4_grid, 256, 0, stream>>>(
        x, W1t, bufG, N, gemm_grid, src, dst, cnt, bucket, E);
    // dinv + pre-scale bufG rows by dinv[src] (kills per-edge dinv gathers)
    scale_dinv<<<(N + 3) / 4, 256, 0, stream>>>(cnt, dinv, bufG, N);
    // fused agg1 + layer-2 GEMM (32-node tiles; bufH pre-scaled in phase B)
    agg_gemm<<<ag_grid, 256, 0, stream>>>(bufG, bucket, cnt, dinv, b1, W2t, bufH, N);
    // final agg2 (fp16 out) + pool
    agg_elu<<<agg_grid, 256, 0, stream>>>(bufH, bucket, cnt, dinv, b2, bufBh, N);
    pool_kernel<<<G, 256, 0, stream>>>(bufBh, out, nper, G);
}